// Round 1
// 371.401 us; speedup vs baseline: 1.0757x; 1.0757x over previous
//
#include <hip/hip_runtime.h>
#include <hip/hip_bf16.h>
#include <math.h>

#define B_   2
#define S_   2048
#define HID_ 2048
#define NH_  32
#define NKV_ 8
#define D_   64
#define G_   (NH_/NKV_)
#define M_   (B_*S_)      // 4096

typedef __hip_bfloat16 bf16;
typedef short bf16x8 __attribute__((ext_vector_type(8)));
typedef float f32x4  __attribute__((ext_vector_type(4)));
typedef unsigned short u16x4 __attribute__((ext_vector_type(4)));

__device__ inline unsigned short f2bfu(float f){
    __hip_bfloat16 h = __float2bfloat16(f);
    return __builtin_bit_cast(unsigned short, h);
}

__device__ __forceinline__ float fexp2(float x){
#if __has_builtin(__builtin_amdgcn_exp2f)
    return __builtin_amdgcn_exp2f(x);
#else
    return exp2f(x);
#endif
}

// async global->LDS, 16B per lane. LDS dest = wave-uniform base + lane*16.
__device__ __forceinline__ void async16(const void* g, void* l) {
    __builtin_amdgcn_global_load_lds(
        (const __attribute__((address_space(1))) unsigned int*)g,
        (__attribute__((address_space(3))) unsigned int*)l, 16, 0, 0);
}

// XOR swizzle for 128B (64 ushort) rows: spreads the 16B slot across banks.
// Bijective per row; preserves 8-ushort (16B) and 4-ushort (8B) alignment.
#define SWZ(r, c) ((c) ^ (((r) & 7) << 3))

// ---------------------------------------------------------------------------
// fp32 -> bf16 bulk convert (8 elems/thread)
// ---------------------------------------------------------------------------
__global__ __launch_bounds__(256) void cvt_k(
    const float* __restrict__ src, bf16* __restrict__ dst, int n)
{
    const int i = (blockIdx.x * 256 + threadIdx.x) * 8;
    if (i >= n) return;
    const float4 a = *(const float4*)(src + i);
    const float4 b = *(const float4*)(src + i + 4);
    uint4 u;
    u.x = (unsigned)f2bfu(a.x) | ((unsigned)f2bfu(a.y) << 16);
    u.y = (unsigned)f2bfu(a.z) | ((unsigned)f2bfu(a.w) << 16);
    u.z = (unsigned)f2bfu(b.x) | ((unsigned)f2bfu(b.y) << 16);
    u.w = (unsigned)f2bfu(b.z) | ((unsigned)f2bfu(b.w) << 16);
    *(uint4*)((unsigned short*)dst + i) = u;
}

// ---------------------------------------------------------------------------
// Transpose + convert: dst[n][k] (bf16) = src_seg[k][n] (fp32).
// ---------------------------------------------------------------------------
__global__ __launch_bounds__(256) void wtrans_k(
    const float* __restrict__ s0, int N0,
    const float* __restrict__ s1, int N1,
    const float* __restrict__ s2, int N2,
    bf16* __restrict__ dst, int K)
{
    __shared__ unsigned short t[64][65];
    const int ntile = blockIdx.x * 64, ktile = blockIdx.y * 64;
    const float* src; int nloc, Nseg;
    if (ntile < N0)           { src = s0; nloc = ntile;           Nseg = N0; }
    else if (ntile < N0 + N1) { src = s1; nloc = ntile - N0;      Nseg = N1; }
    else                      { src = s2; nloc = ntile - N0 - N1; Nseg = N2; }
    const int r  = threadIdx.x >> 4;
    const int c4 = (threadIdx.x & 15) * 4;
    #pragma unroll
    for (int p = 0; p < 4; p++) {
        const int k = p * 16 + r;
        const float4 f = *(const float4*)(src + (size_t)(ktile + k) * Nseg + nloc + c4);
        t[k][c4+0] = f2bfu(f.x); t[k][c4+1] = f2bfu(f.y);
        t[k][c4+2] = f2bfu(f.z); t[k][c4+3] = f2bfu(f.w);
    }
    __syncthreads();
    #pragma unroll
    for (int p = 0; p < 4; p++) {
        const int n = p * 16 + r;
        u16x4 u = { t[c4+0][n], t[c4+1][n], t[c4+2][n], t[c4+3][n] };
        *(u16x4*)((unsigned short*)dst + (size_t)(ntile + n) * K + ktile + c4) = u;
    }
}

// ---------------------------------------------------------------------------
// RoPE cos/sin table (double precision); int32/int64 position_ids handled.
// ---------------------------------------------------------------------------
__global__ __launch_bounds__(256) void rope_tab_k(
    const int* __restrict__ pos, float* __restrict__ ctab, float* __restrict__ stab)
{
    const int idx = blockIdx.x * 256 + threadIdx.x;
    if (idx >= S_ * 32) return;
    const int s = idx >> 5, i = idx & 31;
    const int is64 = (pos[1] == 0);
    const int p = is64 ? pos[2 * s] : pos[s];
    const double inv = exp(-(double)i * (log(150000.0) / 32.0));
    const double f = (double)p * inv;
    ctab[idx] = (float)cos(f);
    stab[idx] = (float)sin(f);
}

// ---------------------------------------------------------------------------
// m97-style MFMA GEMM: C = A[M,2048] @ WT[N,2048]^T, 128x128 tile, BK=64.
// MODE 0: QKV (Q gets RoPE + 0.125*log2e scale -> exp2-domain attention;
//              K gets RoPE; V stored transposed [B*NKV*64][S]).
// MODE 1: OUT (fp32 store + bias b0).
// ---------------------------------------------------------------------------
template<int MODE>
__global__ __launch_bounds__(256) void gemm128_k(
    const bf16* __restrict__ A, const bf16* __restrict__ WT,
    const float* __restrict__ b0, const float* __restrict__ b1,
    const float* __restrict__ b2,
    bf16* __restrict__ Cq, bf16* __restrict__ Ck, bf16* __restrict__ Cv,
    float* __restrict__ Cout,
    const float* __restrict__ ctab, const float* __restrict__ stab)
{
    __shared__ unsigned short sA[128 * 64];
    __shared__ unsigned short sB[128 * 64];

    const int tid  = threadIdx.x;
    const int wave = tid >> 6, lane = tid & 63;
    const int li   = lane & 15, lj = lane >> 4;
    const int m0   = blockIdx.y * 128;
    const int n0   = blockIdx.x * 128;
    const int wm   = (wave >> 1) * 64, wn = (wave & 1) * 64;
    const int K    = 2048;

    f32x4 acc[4][4];
    #pragma unroll
    for (int i = 0; i < 4; i++)
        #pragma unroll
        for (int j = 0; j < 4; j++)
            acc[i][j] = (f32x4){0.f, 0.f, 0.f, 0.f};

    const bf16* ag = A  + (size_t)(m0 + wave * 32 + (lane >> 3)) * K + (lane & 7) * 8;
    const bf16* bg = WT + (size_t)(n0 + wave * 32 + (lane >> 3)) * K + (lane & 7) * 8;
    unsigned short* la = &sA[(wave * 32) * 64];
    unsigned short* lb = &sB[(wave * 32) * 64];

    for (int k0 = 0; k0 < K; k0 += 64) {
        __syncthreads();
        #pragma unroll
        for (int i = 0; i < 4; i++) {
            async16(ag + k0 + (size_t)i * 8 * K, la + i * 8 * 64);
            async16(bg + k0 + (size_t)i * 8 * K, lb + i * 8 * 64);
        }
        __syncthreads();

        #pragma unroll
        for (int ks = 0; ks < 64; ks += 32) {
            bf16x8 af[4], bfr[4];
            #pragma unroll
            for (int mt = 0; mt < 4; mt++)
                af[mt] = *(const bf16x8*)&sA[(wm + mt * 16 + li) * 64 + ks + lj * 8];
            #pragma unroll
            for (int nt = 0; nt < 4; nt++)
                bfr[nt] = *(const bf16x8*)&sB[(wn + nt * 16 + li) * 64 + ks + lj * 8];
            #pragma unroll
            for (int mt = 0; mt < 4; mt++)
                #pragma unroll
                for (int nt = 0; nt < 4; nt++)
                    acc[mt][nt] = __builtin_amdgcn_mfma_f32_16x16x32_bf16(
                        af[mt], bfr[nt], acc[mt][nt], 0, 0, 0);
        }
    }

    if (MODE == 1) {
        #pragma unroll
        for (int mt = 0; mt < 4; mt++)
            #pragma unroll
            for (int nt = 0; nt < 4; nt++) {
                const int col = n0 + wn + nt * 16 + li;
                const float bb = b0[col];
                #pragma unroll
                for (int r = 0; r < 4; r++) {
                    const int row = m0 + wm + mt * 16 + lj * 4 + r;
                    Cout[(size_t)row * HID_ + col] = acc[mt][nt][r] + bb;
                }
            }
        return;
    }

    int seg, cb; const float* bias;
    if (n0 < 2048)      { seg = 0; cb = n0;        bias = b0; }
    else if (n0 < 2560) { seg = 1; cb = n0 - 2048; bias = b1; }
    else                { seg = 2; cb = n0 - 2560; bias = b2; }

    float bl[4];
    #pragma unroll
    for (int nt = 0; nt < 4; nt++) bl[nt] = bias[cb + wn + nt * 16 + li];

    if (seg == 2) {
        const int b = m0 >> 11;
        #pragma unroll
        for (int nt = 0; nt < 4; nt++) {
            const int cseg = cb + wn + nt * 16 + li;
            const int hv = cseg >> 6, d = cseg & 63;
            #pragma unroll
            for (int mt = 0; mt < 4; mt++) {
                const int sb = (m0 & (S_ - 1)) + wm + mt * 16 + lj * 4;
                u16x4 u = { f2bfu(acc[mt][nt][0] + bl[nt]),
                            f2bfu(acc[mt][nt][1] + bl[nt]),
                            f2bfu(acc[mt][nt][2] + bl[nt]),
                            f2bfu(acc[mt][nt][3] + bl[nt]) };
                *(u16x4*)((unsigned short*)Cv +
                    ((size_t)((b * NKV_ + hv) * 64 + d)) * S_ + sb) = u;
            }
        }
        return;
    }

    // Q/K: fused RoPE. Q also folds 0.125 * log2(e) (exp2-domain softmax).
    const float qs = (seg == 0) ? 0.18033688011112042f : 1.0f;
    #pragma unroll
    for (int mt = 0; mt < 4; mt++) {
        #pragma unroll
        for (int r = 0; r < 4; r++) {
            const int row = m0 + wm + mt * 16 + lj * 4 + r;
            const int s = row & (S_ - 1);
            const float c0  = ctab[s * 32 + li],      sn0 = stab[s * 32 + li];
            const float c1  = ctab[s * 32 + 16 + li], sn1 = stab[s * 32 + 16 + li];
            const float x0 = acc[mt][0][r] + bl[0];
            const float x1 = acc[mt][1][r] + bl[1];
            const float x2 = acc[mt][2][r] + bl[2];
            const float x3 = acc[mt][3][r] + bl[3];
            const float y0 = (x0 * c0 - x2 * sn0) * qs;
            const float y2 = (x2 * c0 + x0 * sn0) * qs;
            const float y1 = (x1 * c1 - x3 * sn1) * qs;
            const float y3 = (x3 * c1 + x1 * sn1) * qs;
            if (seg == 0) {
                bf16* cp = Cq + (size_t)row * HID_ + n0 + wn + li;
                cp[0]  = __float2bfloat16(y0);
                cp[16] = __float2bfloat16(y1);
                cp[32] = __float2bfloat16(y2);
                cp[48] = __float2bfloat16(y3);
            } else {
                bf16* cp = Ck + (size_t)row * 512 + cb + wn + li;
                cp[0]  = __float2bfloat16(y0);
                cp[16] = __float2bfloat16(y1);
                cp[32] = __float2bfloat16(y2);
                cp[48] = __float2bfloat16(y3);
            }
        }
    }
}

// ---------------------------------------------------------------------------
// MFMA flash attention v2.
//   - QBLK=128 per block, 32 q-rows per wave (2 q-groups of 16): K/V LDS
//     fragments are q-independent, so each kf/vf read now feeds TWO MFMAs
//     (halves LDS read traffic per unit work — the kernel was LDS-pipe-bound).
//   - XOR-swizzled LDS (SWZ): 128B rows, ds_read_b128 / writes hit the b128
//     minimum of 8 requests/bank (old 72-pad layout measured 2.3e7 conflict cy).
//   - T14 reg-prefetch: next K/V tile's global loads issued right after the
//     staging barrier, consumed at next iter's ds_write (latency hidden under
//     MFMA+softmax).
//   - T13 defer-max (THR=8, exp2 domain): skip O/l rescale unless the tile max
//     grows by >8; P bounded by 2^8, fine in bf16.
//   - Lane-local l accumulation; cross-lj reduction once in epilogue.
// ---------------------------------------------------------------------------
__global__ __launch_bounds__(256, 4) void attn_k(
    const bf16* __restrict__ qws, const bf16* __restrict__ kws,
    const bf16* __restrict__ vtw, bf16* __restrict__ ows)
{
    __shared__ unsigned short sK [64 * 64];     // [key][dim], swizzled
    __shared__ unsigned short sVt[64 * 64];     // [dim][key], swizzled
    __shared__ unsigned short sP [4 * 32 * 64]; // per-wave [2*16 q][key], swizzled

    const int tid  = threadIdx.x;
    const int wave = tid >> 6, lane = tid & 63;
    const int li   = lane & 15, lj = lane >> 4;
    const int bh   = blockIdx.y;
    const int q0   = blockIdx.x * 128;
    const int b    = bh / NH_, h = bh % NH_;
    const int hk   = h / G_;

    bf16x8 qf[2][2];
    #pragma unroll
    for (int g = 0; g < 2; g++) {
        const bf16* qp = qws + (size_t)(b * S_ + q0 + wave * 32 + g * 16 + li) * HID_
                         + h * D_ + lj * 8;
        qf[g][0] = *(const bf16x8*)(qp);
        qf[g][1] = *(const bf16x8*)(qp + 32);
    }

    f32x4 o[2][4];
    #pragma unroll
    for (int g = 0; g < 2; g++)
        #pragma unroll
        for (int mt = 0; mt < 4; mt++) o[g][mt] = (f32x4){0.f, 0.f, 0.f, 0.f};
    float mr[2] = {-1e30f, -1e30f};
    float ll[2] = {0.f, 0.f};

    const int srow = tid >> 2, scol = (tid & 3) * 16;
    const bf16* kb = kws + (size_t)b * S_ * 512 + hk * 64;
    const bf16* vb = vtw + (size_t)((b * NKV_ + hk) * 64) * S_;
    unsigned short* sp = sP + wave * (32 * 64);

    // prefetch tile 0 into registers
    uint4 pk0, pk1, pv0, pv1;
    {
        const uint4* kp = (const uint4*)(kb + (size_t)srow * 512 + scol);
        const uint4* vp = (const uint4*)(vb + (size_t)srow * S_ + scol);
        pk0 = kp[0]; pk1 = kp[1]; pv0 = vp[0]; pv1 = vp[1];
    }

    for (int kt = 0; kt < S_; kt += 64) {
        __syncthreads();   // previous tile's frag reads done
        *(uint4*)&sK [srow * 64 + SWZ(srow, scol)]     = pk0;
        *(uint4*)&sK [srow * 64 + SWZ(srow, scol + 8)] = pk1;
        *(uint4*)&sVt[srow * 64 + SWZ(srow, scol)]     = pv0;
        *(uint4*)&sVt[srow * 64 + SWZ(srow, scol + 8)] = pv1;
        __syncthreads();

        // issue next tile's global loads; latency hides under compute below
        if (kt + 64 < S_) {
            const uint4* kp = (const uint4*)(kb + (size_t)(kt + 64 + srow) * 512 + scol);
            const uint4* vp = (const uint4*)(vb + (size_t)srow * S_ + kt + 64 + scol);
            pk0 = kp[0]; pk1 = kp[1]; pv0 = vp[0]; pv1 = vp[1];
        }

        // St = K·Q^T for both q-groups: kf shared across groups.
        // lane holds score(q = g*16 + li, key = kt + nt*16 + lj*4 + r)
        float sc[2][4][4];
        __builtin_amdgcn_s_setprio(1);
        #pragma unroll
        for (int nt = 0; nt < 4; nt++) {
            f32x4 c0 = (f32x4){0.f, 0.f, 0.f, 0.f};
            f32x4 c1 = (f32x4){0.f, 0.f, 0.f, 0.f};
            #pragma unroll
            for (int ks = 0; ks < 2; ks++) {
                const bf16x8 kf =
                    *(const bf16x8*)&sK[(nt * 16 + li) * 64 + SWZ(li, ks * 32 + lj * 8)];
                c0 = __builtin_amdgcn_mfma_f32_16x16x32_bf16(kf, qf[0][ks], c0, 0, 0, 0);
                c1 = __builtin_amdgcn_mfma_f32_16x16x32_bf16(kf, qf[1][ks], c1, 0, 0, 0);
            }
            #pragma unroll
            for (int r = 0; r < 4; r++) { sc[0][nt][r] = c0[r]; sc[1][nt][r] = c1[r]; }
        }
        __builtin_amdgcn_s_setprio(0);

        // online softmax per q-group (exp2 domain; Q pre-scaled by 0.125*log2e)
        #pragma unroll
        for (int g = 0; g < 2; g++) {
            float cm = sc[g][0][0];
            #pragma unroll
            for (int nt = 0; nt < 4; nt++)
                #pragma unroll
                for (int r = 0; r < 4; r++) cm = fmaxf(cm, sc[g][nt][r]);
            cm = fmaxf(cm, __shfl_xor(cm, 16));
            cm = fmaxf(cm, __shfl_xor(cm, 32));
            // defer-max: only rescale when the running max grows by > 8
            if (!__all(cm - mr[g] <= 8.0f)) {
                const float mnew = fmaxf(mr[g], cm);
                const float al   = fexp2(mr[g] - mnew);
                mr[g] = mnew;
                ll[g] *= al;
                #pragma unroll
                for (int mt = 0; mt < 4; mt++) o[g][mt] *= al;
            }
            float rs = 0.f;
            #pragma unroll
            for (int nt = 0; nt < 4; nt++) {
                const float e0 = fexp2(sc[g][nt][0] - mr[g]);
                const float e1 = fexp2(sc[g][nt][1] - mr[g]);
                const float e2 = fexp2(sc[g][nt][2] - mr[g]);
                const float e3 = fexp2(sc[g][nt][3] - mr[g]);
                rs += (e0 + e1) + (e2 + e3);
                u16x4 u = { f2bfu(e0), f2bfu(e1), f2bfu(e2), f2bfu(e3) };
                *(u16x4*)&sp[(g * 16 + li) * 64 + SWZ(li, nt * 16 + lj * 4)] = u;
            }
            ll[g] += rs;   // lane-local partial; reduced once in epilogue
        }

        // O^T = V^T·P^T: vf shared across both q-groups
        __builtin_amdgcn_s_setprio(1);
        #pragma unroll
        for (int ks = 0; ks < 2; ks++) {
            const bf16x8 pf0 = *(const bf16x8*)&sp[(li)      * 64 + SWZ(li, ks * 32 + lj * 8)];
            const bf16x8 pf1 = *(const bf16x8*)&sp[(16 + li) * 64 + SWZ(li, ks * 32 + lj * 8)];
            #pragma unroll
            for (int mt = 0; mt < 4; mt++) {
                const bf16x8 vf =
                    *(const bf16x8*)&sVt[(mt * 16 + li) * 64 + SWZ(li, ks * 32 + lj * 8)];
                o[0][mt] = __builtin_amdgcn_mfma_f32_16x16x32_bf16(vf, pf0, o[0][mt], 0, 0, 0);
                o[1][mt] = __builtin_amdgcn_mfma_f32_16x16x32_bf16(vf, pf1, o[1][mt], 0, 0, 0);
            }
        }
        __builtin_amdgcn_s_setprio(0);
    }

    // epilogue: lane holds O[q = g*16 + li][dim = mt*16 + lj*4 + r]
    #pragma unroll
    for (int g = 0; g < 2; g++) {
        float l = ll[g];
        l += __shfl_xor(l, 16);
        l += __shfl_xor(l, 32);
        const float inv = 1.0f / l;
        bf16* op = ows + (size_t)(b * S_ + q0 + wave * 32 + g * 16 + li) * HID_ + h * D_;
        #pragma unroll
        for (int mt = 0; mt < 4; mt++) {
            u16x4 u = { f2bfu(o[g][mt][0] * inv), f2bfu(o[g][mt][1] * inv),
                        f2bfu(o[g][mt][2] * inv), f2bfu(o[g][mt][3] * inv) };
            *(u16x4*)((unsigned short*)op + mt * 16 + lj * 4) = u;
        }
    }
}

// ---------------------------------------------------------------------------
extern "C" void kernel_launch(void* const* d_in, const int* in_sizes, int n_in,
                              void* d_out, int out_size, void* d_ws, size_t ws_size,
                              hipStream_t stream)
{
    const float* hs  = (const float*)d_in[0];
    const int*   pos = (const int*)d_in[1];
    const float* wq = (const float*)d_in[2];
    const float* bq = (const float*)d_in[3];
    const float* wk = (const float*)d_in[4];
    const float* bk = (const float*)d_in[5];
    const float* wv = (const float*)d_in[6];
    const float* bv = (const float*)d_in[7];
    const float* wo = (const float*)d_in[8];
    const float* bo = (const float*)d_in[9];

    // workspace (52.5 MB peak)
    char* ws = (char*)d_ws;
    float* ctab  = (float*)(ws);
    float* stab  = (float*)(ws + (256u << 10));
    bf16*  k_ws  = (bf16*)(ws + (512u << 10));
    bf16*  v_t   = (bf16*)(ws + (512u << 10) + (4u  << 20));
    bf16*  q_ws  = (bf16*)(ws + (512u << 10) + (8u  << 20));
    bf16*  woT   = q_ws;                                   // overlay
    bf16*  hs_b  = (bf16*)(ws + (512u << 10) + (24u << 20));
    bf16*  o_ws  = hs_b;                                   // overlay
    bf16*  wqkvT = (bf16*)(ws + (512u << 10) + (40u << 20));

    rope_tab_k<<<dim3(256), dim3(256), 0, stream>>>(pos, ctab, stab);

    cvt_k<<<dim3(M_ * HID_ / 2048), dim3(256), 0, stream>>>(hs, hs_b, M_ * HID_);

    wtrans_k<<<dim3(48, 32), dim3(256), 0, stream>>>(
        wq, 2048, wk, 512, wv, 512, wqkvT, HID_);

    gemm128_k<0><<<dim3(24, 32), dim3(256), 0, stream>>>(
        hs_b, wqkvT, bq, bk, bv, q_ws, k_ws, v_t, nullptr, ctab, stab);

    attn_k<<<dim3(S_ / 128, B_ * NH_), dim3(256), 0, stream>>>(q_ws, k_ws, v_t, o_ws);

    wtrans_k<<<dim3(32, 32), dim3(256), 0, stream>>>(
        wo, 2048, wo, 0, wo, 0, woT, HID_);

    gemm128_k<1><<<dim3(16, 32), dim3(256), 0, stream>>>(
        o_ws, woT, bo, nullptr, nullptr, nullptr, nullptr, nullptr,
        (float*)d_out, nullptr, nullptr);
}

// Round 2
// 347.436 us; speedup vs baseline: 1.1499x; 1.0690x over previous
//
#include <hip/hip_runtime.h>
#include <hip/hip_bf16.h>
#include <math.h>

#define B_   2
#define S_   2048
#define HID_ 2048
#define NH_  32
#define NKV_ 8
#define D_   64
#define G_   (NH_/NKV_)
#define M_   (B_*S_)      // 4096

typedef __hip_bfloat16 bf16;
typedef short bf16x8 __attribute__((ext_vector_type(8)));
typedef float f32x4  __attribute__((ext_vector_type(4)));
typedef unsigned short u16x4 __attribute__((ext_vector_type(4)));

__device__ inline unsigned short f2bfu(float f){
    __hip_bfloat16 h = __float2bfloat16(f);
    return __builtin_bit_cast(unsigned short, h);
}

__device__ __forceinline__ float fexp2(float x){
#if __has_builtin(__builtin_amdgcn_exp2f)
    return __builtin_amdgcn_exp2f(x);
#else
    return exp2f(x);
#endif
}

// async global->LDS, 16B per lane. LDS dest = wave-uniform base + lane*16.
__device__ __forceinline__ void async16(const void* g, void* l) {
    __builtin_amdgcn_global_load_lds(
        (const __attribute__((address_space(1))) unsigned int*)g,
        (__attribute__((address_space(3))) unsigned int*)l, 16, 0, 0);
}

// XOR swizzle for 128B (64 ushort) rows (attn): spreads 16B slots across banks.
#define SWZ(r, c) ((c) ^ (((r) & 7) << 3))

// raw barrier + counted waitcnt (compiler memory fences via asm clobbers)
#define S_BARRIER() asm volatile("s_barrier" ::: "memory")
__device__ __forceinline__ void vmwait8(){ asm volatile("s_waitcnt vmcnt(8)" ::: "memory"); }
__device__ __forceinline__ void vmwait6(){ asm volatile("s_waitcnt vmcnt(6)" ::: "memory"); }
__device__ __forceinline__ void vmwait0(){ asm volatile("s_waitcnt vmcnt(0)" ::: "memory"); }

// ---------------------------------------------------------------------------
// fp32 -> bf16 bulk convert (8 elems/thread)
// ---------------------------------------------------------------------------
__global__ __launch_bounds__(256) void cvt_k(
    const float* __restrict__ src, bf16* __restrict__ dst, int n)
{
    const int i = (blockIdx.x * 256 + threadIdx.x) * 8;
    if (i >= n) return;
    const float4 a = *(const float4*)(src + i);
    const float4 b = *(const float4*)(src + i + 4);
    uint4 u;
    u.x = (unsigned)f2bfu(a.x) | ((unsigned)f2bfu(a.y) << 16);
    u.y = (unsigned)f2bfu(a.z) | ((unsigned)f2bfu(a.w) << 16);
    u.z = (unsigned)f2bfu(b.x) | ((unsigned)f2bfu(b.y) << 16);
    u.w = (unsigned)f2bfu(b.z) | ((unsigned)f2bfu(b.w) << 16);
    *(uint4*)((unsigned short*)dst + i) = u;
}

// ---------------------------------------------------------------------------
// Transpose + convert: dst[n][k] (bf16) = src_seg[k][n] (fp32).
// ---------------------------------------------------------------------------
__global__ __launch_bounds__(256) void wtrans_k(
    const float* __restrict__ s0, int N0,
    const float* __restrict__ s1, int N1,
    const float* __restrict__ s2, int N2,
    bf16* __restrict__ dst, int K)
{
    __shared__ unsigned short t[64][65];
    const int ntile = blockIdx.x * 64, ktile = blockIdx.y * 64;
    const float* src; int nloc, Nseg;
    if (ntile < N0)           { src = s0; nloc = ntile;           Nseg = N0; }
    else if (ntile < N0 + N1) { src = s1; nloc = ntile - N0;      Nseg = N1; }
    else                      { src = s2; nloc = ntile - N0 - N1; Nseg = N2; }
    const int r  = threadIdx.x >> 4;
    const int c4 = (threadIdx.x & 15) * 4;
    #pragma unroll
    for (int p = 0; p < 4; p++) {
        const int k = p * 16 + r;
        const float4 f = *(const float4*)(src + (size_t)(ktile + k) * Nseg + nloc + c4);
        t[k][c4+0] = f2bfu(f.x); t[k][c4+1] = f2bfu(f.y);
        t[k][c4+2] = f2bfu(f.z); t[k][c4+3] = f2bfu(f.w);
    }
    __syncthreads();
    #pragma unroll
    for (int p = 0; p < 4; p++) {
        const int n = p * 16 + r;
        u16x4 u = { t[c4+0][n], t[c4+1][n], t[c4+2][n], t[c4+3][n] };
        *(u16x4*)((unsigned short*)dst + (size_t)(ntile + n) * K + ktile + c4) = u;
    }
}

// ---------------------------------------------------------------------------
// RoPE cos/sin table (double precision); int32/int64 position_ids handled.
// ---------------------------------------------------------------------------
__global__ __launch_bounds__(256) void rope_tab_k(
    const int* __restrict__ pos, float* __restrict__ ctab, float* __restrict__ stab)
{
    const int idx = blockIdx.x * 256 + threadIdx.x;
    if (idx >= S_ * 32) return;
    const int s = idx >> 5, i = idx & 31;
    const int is64 = (pos[1] == 0);
    const int p = is64 ? pos[2 * s] : pos[s];
    const double inv = exp(-(double)i * (log(150000.0) / 32.0));
    const double f = (double)p * inv;
    ctab[idx] = (float)cos(f);
    stab[idx] = (float)sin(f);
}

// ---------------------------------------------------------------------------
// Pipelined 256-wide MFMA GEMM: C = A[M,2048] @ WT[N,2048]^T.
// BM x 256 tile, BK=64, 8 waves (2M x 4N), double-buffered LDS,
// raw s_barrier + counted vmcnt (full K-tile prefetched one tile ahead,
// never drained mid-loop), XOR chunk-swizzled LDS (pre-swizzled global
// source feeding linear global_load_lds; swizzled ds_read_b128 on read).
// MODE 0: QKV epilogue (Q: RoPE + 0.125*log2e; K: RoPE; V: transposed store).
// MODE 1: OUT epilogue (fp32 + bias b0).
// ---------------------------------------------------------------------------

// stage one K-tile (BM x 64 of A, 256 x 64 of B) into LDS buffers.
// LDS is linear; global source chunk is pre-swizzled: chunk = (lane&7)^(lane>>3),
// so LDS row r chunk c holds global chunk c ^ (r&7).
template<int BM>
__device__ __forceinline__ void stage_g(
    const bf16* __restrict__ A, const bf16* __restrict__ B,
    int m0, int n0, int k0,
    unsigned short* sAb, unsigned short* sBb, int wave, int lane)
{
    const int rr = wave * 8 + (lane >> 3);             // row within 64-row round
    const int cc = ((lane & 7) ^ (lane >> 3)) * 8;     // swizzled ushort col
    #pragma unroll
    for (int i = 0; i < BM / 64; ++i)
        async16(A + (size_t)(m0 + i * 64 + rr) * 2048 + k0 + cc,
                sAb + i * 4096 + wave * 512);
    #pragma unroll
    for (int j = 0; j < 4; ++j)
        async16(B + (size_t)(n0 + j * 64 + rr) * 2048 + k0 + cc,
                sBb + j * 4096 + wave * 512);
}

// compute one K-tile (BK=64) from LDS buffer into acc.
template<int BM>
__device__ __forceinline__ void tile_mfma(
    const unsigned short* sAb, const unsigned short* sBb,
    int wm, int wn, int li, int lj, f32x4 (*acc)[4])
{
    constexpr int MT = BM / 32;   // m-frags per wave
    constexpr int PM = MT / 4;    // m-frags per phase (4 phases)
    const int swz = li & 7;

    bf16x8 bfr[4][2];
    #pragma unroll
    for (int nt = 0; nt < 4; ++nt)
        #pragma unroll
        for (int ks = 0; ks < 2; ++ks)
            bfr[nt][ks] = *(const bf16x8*)
                &sBb[(wn * 64 + nt * 16 + li) * 64 + ((ks * 4 + lj) ^ swz) * 8];

    bf16x8 afA[PM][2], afB[PM][2];
    auto lda = [&](bf16x8 (*dst)[2], int p) {
        #pragma unroll
        for (int m = 0; m < PM; ++m)
            #pragma unroll
            for (int ks = 0; ks < 2; ++ks)
                dst[m][ks] = *(const bf16x8*)
                    &sAb[(wm * (BM / 2) + (p * PM + m) * 16 + li) * 64
                         + ((ks * 4 + lj) ^ swz) * 8];
    };
    lda(afA, 0);
    #pragma unroll
    for (int p = 0; p < 4; ++p) {
        bf16x8 (*cur)[2] = (p & 1) ? afB : afA;
        bf16x8 (*nxt)[2] = (p & 1) ? afA : afB;
        if (p < 3) lda(nxt, p + 1);
        __builtin_amdgcn_s_setprio(1);
        #pragma unroll
        for (int ks = 0; ks < 2; ++ks)
            #pragma unroll
            for (int m = 0; m < PM; ++m)
                #pragma unroll
                for (int nt = 0; nt < 4; ++nt)
                    acc[p * PM + m][nt] = __builtin_amdgcn_mfma_f32_16x16x32_bf16(
                        cur[m][ks], bfr[nt][ks], acc[p * PM + m][nt], 0, 0, 0);
        __builtin_amdgcn_s_setprio(0);
        __builtin_amdgcn_sched_barrier(0);
    }
}

template<int MODE, int BM>
__global__ __launch_bounds__(512, 2) void gemm256_k(
    const bf16* __restrict__ A, const bf16* __restrict__ WT,
    const float* __restrict__ b0, const float* __restrict__ b1,
    const float* __restrict__ b2,
    bf16* __restrict__ Cq, bf16* __restrict__ Ck, bf16* __restrict__ Cv,
    float* __restrict__ Cout,
    const float* __restrict__ ctab, const float* __restrict__ stab)
{
    constexpr int MT = BM / 32;
    constexpr int LA = BM * 64;
    constexpr int LB = 256 * 64;
    constexpr int NT = 2048 / 64;  // 32 K-tiles
    __shared__ unsigned short sA[2 * LA];
    __shared__ unsigned short sB[2 * LB];

    const int tid  = threadIdx.x;
    const int wave = tid >> 6, lane = tid & 63;
    const int li   = lane & 15, lj = lane >> 4;
    const int wm   = wave >> 2, wn = wave & 3;
    const int m0   = blockIdx.y * BM;
    const int n0   = blockIdx.x * 256;

    f32x4 acc[MT][4];
    #pragma unroll
    for (int i = 0; i < MT; ++i)
        #pragma unroll
        for (int j = 0; j < 4; ++j)
            acc[i][j] = (f32x4){0.f, 0.f, 0.f, 0.f};

    // prologue: prefetch tiles 0 and 1; wait only for tile 0 (counted).
    stage_g<BM>(A, WT, m0, n0, 0,  sA,      sB,      wave, lane);
    stage_g<BM>(A, WT, m0, n0, 64, sA + LA, sB + LB, wave, lane);
    if constexpr (BM == 256) vmwait8(); else vmwait6();
    S_BARRIER();

    for (int t = 0; t < NT; ++t) {
        const int buf = t & 1;
        tile_mfma<BM>(sA + buf * LA, sB + buf * LB, wm, wn, li, lj, acc);
        S_BARRIER();                       // all waves done reading buf
        if (t + 2 < NT) {
            stage_g<BM>(A, WT, m0, n0, (t + 2) * 64,
                        sA + buf * LA, sB + buf * LB, wave, lane);
            if constexpr (BM == 256) vmwait8(); else vmwait6();  // tile t+1 landed
        } else {
            vmwait0();                     // tail: drain
        }
        S_BARRIER();
    }

    // ------------------------------ epilogue ------------------------------
    if (MODE == 1) {
        #pragma unroll
        for (int mt = 0; mt < MT; ++mt)
            #pragma unroll
            for (int nt = 0; nt < 4; ++nt) {
                const int col = n0 + wn * 64 + nt * 16 + li;
                const float bb = b0[col];
                #pragma unroll
                for (int r = 0; r < 4; ++r) {
                    const int row = m0 + wm * (BM / 2) + mt * 16 + lj * 4 + r;
                    Cout[(size_t)row * HID_ + col] = acc[mt][nt][r] + bb;
                }
            }
        return;
    }

    int seg, cb; const float* bias;
    if (n0 < 2048)      { seg = 0; cb = n0;        bias = b0; }
    else if (n0 < 2560) { seg = 1; cb = n0 - 2048; bias = b1; }
    else                { seg = 2; cb = n0 - 2560; bias = b2; }

    float bl[4];
    #pragma unroll
    for (int nt = 0; nt < 4; ++nt) bl[nt] = bias[cb + wn * 64 + nt * 16 + li];

    if (seg == 2) {
        const int b = m0 >> 11;
        #pragma unroll
        for (int nt = 0; nt < 4; ++nt) {
            const int cseg = cb + wn * 64 + nt * 16 + li;
            const int hv = cseg >> 6, d = cseg & 63;
            #pragma unroll
            for (int mt = 0; mt < MT; ++mt) {
                const int sb = (m0 & (S_ - 1)) + wm * (BM / 2) + mt * 16 + lj * 4;
                u16x4 u = { f2bfu(acc[mt][nt][0] + bl[nt]),
                            f2bfu(acc[mt][nt][1] + bl[nt]),
                            f2bfu(acc[mt][nt][2] + bl[nt]),
                            f2bfu(acc[mt][nt][3] + bl[nt]) };
                *(u16x4*)((unsigned short*)Cv +
                    ((size_t)((b * NKV_ + hv) * 64 + d)) * S_ + sb) = u;
            }
        }
        return;
    }

    // Q/K: fused RoPE. Q also folds 0.125 * log2(e) (exp2-domain softmax).
    const float qs = (seg == 0) ? 0.18033688011112042f : 1.0f;
    #pragma unroll
    for (int mt = 0; mt < MT; ++mt) {
        #pragma unroll
        for (int r = 0; r < 4; ++r) {
            const int row = m0 + wm * (BM / 2) + mt * 16 + lj * 4 + r;
            const int s = row & (S_ - 1);
            const float c0  = ctab[s * 32 + li],      sn0 = stab[s * 32 + li];
            const float c1  = ctab[s * 32 + 16 + li], sn1 = stab[s * 32 + 16 + li];
            const float x0 = acc[mt][0][r] + bl[0];
            const float x1 = acc[mt][1][r] + bl[1];
            const float x2 = acc[mt][2][r] + bl[2];
            const float x3 = acc[mt][3][r] + bl[3];
            const float y0 = (x0 * c0 - x2 * sn0) * qs;
            const float y2 = (x2 * c0 + x0 * sn0) * qs;
            const float y1 = (x1 * c1 - x3 * sn1) * qs;
            const float y3 = (x3 * c1 + x1 * sn1) * qs;
            if (seg == 0) {
                bf16* cp = Cq + (size_t)row * HID_ + n0 + wn * 64 + li;
                cp[0]  = __float2bfloat16(y0);
                cp[16] = __float2bfloat16(y1);
                cp[32] = __float2bfloat16(y2);
                cp[48] = __float2bfloat16(y3);
            } else {
                bf16* cp = Ck + (size_t)row * 512 + cb + wn * 64 + li;
                cp[0]  = __float2bfloat16(y0);
                cp[16] = __float2bfloat16(y1);
                cp[32] = __float2bfloat16(y2);
                cp[48] = __float2bfloat16(y3);
            }
        }
    }
}

// ---------------------------------------------------------------------------
// MFMA flash attention (unchanged from round 1 — verified at 114.6 us).
// ---------------------------------------------------------------------------
__global__ __launch_bounds__(256, 4) void attn_k(
    const bf16* __restrict__ qws, const bf16* __restrict__ kws,
    const bf16* __restrict__ vtw, bf16* __restrict__ ows)
{
    __shared__ unsigned short sK [64 * 64];     // [key][dim], swizzled
    __shared__ unsigned short sVt[64 * 64];     // [dim][key], swizzled
    __shared__ unsigned short sP [4 * 32 * 64]; // per-wave [2*16 q][key], swizzled

    const int tid  = threadIdx.x;
    const int wave = tid >> 6, lane = tid & 63;
    const int li   = lane & 15, lj = lane >> 4;
    const int bh   = blockIdx.y;
    const int q0   = blockIdx.x * 128;
    const int b    = bh / NH_, h = bh % NH_;
    const int hk   = h / G_;

    bf16x8 qf[2][2];
    #pragma unroll
    for (int g = 0; g < 2; g++) {
        const bf16* qp = qws + (size_t)(b * S_ + q0 + wave * 32 + g * 16 + li) * HID_
                         + h * D_ + lj * 8;
        qf[g][0] = *(const bf16x8*)(qp);
        qf[g][1] = *(const bf16x8*)(qp + 32);
    }

    f32x4 o[2][4];
    #pragma unroll
    for (int g = 0; g < 2; g++)
        #pragma unroll
        for (int mt = 0; mt < 4; mt++) o[g][mt] = (f32x4){0.f, 0.f, 0.f, 0.f};
    float mr[2] = {-1e30f, -1e30f};
    float ll[2] = {0.f, 0.f};

    const int srow = tid >> 2, scol = (tid & 3) * 16;
    const bf16* kb = kws + (size_t)b * S_ * 512 + hk * 64;
    const bf16* vb = vtw + (size_t)((b * NKV_ + hk) * 64) * S_;
    unsigned short* sp = sP + wave * (32 * 64);

    uint4 pk0, pk1, pv0, pv1;
    {
        const uint4* kp = (const uint4*)(kb + (size_t)srow * 512 + scol);
        const uint4* vp = (const uint4*)(vb + (size_t)srow * S_ + scol);
        pk0 = kp[0]; pk1 = kp[1]; pv0 = vp[0]; pv1 = vp[1];
    }

    for (int kt = 0; kt < S_; kt += 64) {
        __syncthreads();
        *(uint4*)&sK [srow * 64 + SWZ(srow, scol)]     = pk0;
        *(uint4*)&sK [srow * 64 + SWZ(srow, scol + 8)] = pk1;
        *(uint4*)&sVt[srow * 64 + SWZ(srow, scol)]     = pv0;
        *(uint4*)&sVt[srow * 64 + SWZ(srow, scol + 8)] = pv1;
        __syncthreads();

        if (kt + 64 < S_) {
            const uint4* kp = (const uint4*)(kb + (size_t)(kt + 64 + srow) * 512 + scol);
            const uint4* vp = (const uint4*)(vb + (size_t)srow * S_ + kt + 64 + scol);
            pk0 = kp[0]; pk1 = kp[1]; pv0 = vp[0]; pv1 = vp[1];
        }

        float sc[2][4][4];
        __builtin_amdgcn_s_setprio(1);
        #pragma unroll
        for (int nt = 0; nt < 4; nt++) {
            f32x4 c0 = (f32x4){0.f, 0.f, 0.f, 0.f};
            f32x4 c1 = (f32x4){0.f, 0.f, 0.f, 0.f};
            #pragma unroll
            for (int ks = 0; ks < 2; ks++) {
                const bf16x8 kf =
                    *(const bf16x8*)&sK[(nt * 16 + li) * 64 + SWZ(li, ks * 32 + lj * 8)];
                c0 = __builtin_amdgcn_mfma_f32_16x16x32_bf16(kf, qf[0][ks], c0, 0, 0, 0);
                c1 = __builtin_amdgcn_mfma_f32_16x16x32_bf16(kf, qf[1][ks], c1, 0, 0, 0);
            }
            #pragma unroll
            for (int r = 0; r < 4; r++) { sc[0][nt][r] = c0[r]; sc[1][nt][r] = c1[r]; }
        }
        __builtin_amdgcn_s_setprio(0);

        #pragma unroll
        for (int g = 0; g < 2; g++) {
            float cm = sc[g][0][0];
            #pragma unroll
            for (int nt = 0; nt < 4; nt++)
                #pragma unroll
                for (int r = 0; r < 4; r++) cm = fmaxf(cm, sc[g][nt][r]);
            cm = fmaxf(cm, __shfl_xor(cm, 16));
            cm = fmaxf(cm, __shfl_xor(cm, 32));
            if (!__all(cm - mr[g] <= 8.0f)) {
                const float mnew = fmaxf(mr[g], cm);
                const float al   = fexp2(mr[g] - mnew);
                mr[g] = mnew;
                ll[g] *= al;
                #pragma unroll
                for (int mt = 0; mt < 4; mt++) o[g][mt] *= al;
            }
            float rs = 0.f;
            #pragma unroll
            for (int nt = 0; nt < 4; nt++) {
                const float e0 = fexp2(sc[g][nt][0] - mr[g]);
                const float e1 = fexp2(sc[g][nt][1] - mr[g]);
                const float e2 = fexp2(sc[g][nt][2] - mr[g]);
                const float e3 = fexp2(sc[g][nt][3] - mr[g]);
                rs += (e0 + e1) + (e2 + e3);
                u16x4 u = { f2bfu(e0), f2bfu(e1), f2bfu(e2), f2bfu(e3) };
                *(u16x4*)&sp[(g * 16 + li) * 64 + SWZ(li, nt * 16 + lj * 4)] = u;
            }
            ll[g] += rs;
        }

        __builtin_amdgcn_s_setprio(1);
        #pragma unroll
        for (int ks = 0; ks < 2; ks++) {
            const bf16x8 pf0 = *(const bf16x8*)&sp[(li)      * 64 + SWZ(li, ks * 32 + lj * 8)];
            const bf16x8 pf1 = *(const bf16x8*)&sp[(16 + li) * 64 + SWZ(li, ks * 32 + lj * 8)];
            #pragma unroll
            for (int mt = 0; mt < 4; mt++) {
                const bf16x8 vf =
                    *(const bf16x8*)&sVt[(mt * 16 + li) * 64 + SWZ(li, ks * 32 + lj * 8)];
                o[0][mt] = __builtin_amdgcn_mfma_f32_16x16x32_bf16(vf, pf0, o[0][mt], 0, 0, 0);
                o[1][mt] = __builtin_amdgcn_mfma_f32_16x16x32_bf16(vf, pf1, o[1][mt], 0, 0, 0);
            }
        }
        __builtin_amdgcn_s_setprio(0);
    }

    #pragma unroll
    for (int g = 0; g < 2; g++) {
        float l = ll[g];
        l += __shfl_xor(l, 16);
        l += __shfl_xor(l, 32);
        const float inv = 1.0f / l;
        bf16* op = ows + (size_t)(b * S_ + q0 + wave * 32 + g * 16 + li) * HID_ + h * D_;
        #pragma unroll
        for (int mt = 0; mt < 4; mt++) {
            u16x4 u = { f2bfu(o[g][mt][0] * inv), f2bfu(o[g][mt][1] * inv),
                        f2bfu(o[g][mt][2] * inv), f2bfu(o[g][mt][3] * inv) };
            *(u16x4*)((unsigned short*)op + mt * 16 + lj * 4) = u;
        }
    }
}

// ---------------------------------------------------------------------------
extern "C" void kernel_launch(void* const* d_in, const int* in_sizes, int n_in,
                              void* d_out, int out_size, void* d_ws, size_t ws_size,
                              hipStream_t stream)
{
    const float* hs  = (const float*)d_in[0];
    const int*   pos = (const int*)d_in[1];
    const float* wq = (const float*)d_in[2];
    const float* bq = (const float*)d_in[3];
    const float* wk = (const float*)d_in[4];
    const float* bk = (const float*)d_in[5];
    const float* wv = (const float*)d_in[6];
    const float* bv = (const float*)d_in[7];
    const float* wo = (const float*)d_in[8];
    const float* bo = (const float*)d_in[9];

    // workspace (52.5 MB peak)
    char* ws = (char*)d_ws;
    float* ctab  = (float*)(ws);
    float* stab  = (float*)(ws + (256u << 10));
    bf16*  k_ws  = (bf16*)(ws + (512u << 10));
    bf16*  v_t   = (bf16*)(ws + (512u << 10) + (4u  << 20));
    bf16*  q_ws  = (bf16*)(ws + (512u << 10) + (8u  << 20));
    bf16*  woT   = q_ws;                                   // overlay
    bf16*  hs_b  = (bf16*)(ws + (512u << 10) + (24u << 20));
    bf16*  o_ws  = hs_b;                                   // overlay
    bf16*  wqkvT = (bf16*)(ws + (512u << 10) + (40u << 20));

    rope_tab_k<<<dim3(256), dim3(256), 0, stream>>>(pos, ctab, stab);

    cvt_k<<<dim3(M_ * HID_ / 2048), dim3(256), 0, stream>>>(hs, hs_b, M_ * HID_);

    wtrans_k<<<dim3(48, 32), dim3(256), 0, stream>>>(
        wq, 2048, wk, 512, wv, 512, wqkvT, HID_);

    // QKV: BM=256, BN=256 -> grid 12 x 16 = 192 blocks (1/CU)
    gemm256_k<0, 256><<<dim3(12, 16), dim3(512), 0, stream>>>(
        hs_b, wqkvT, bq, bk, bv, q_ws, k_ws, v_t, nullptr, ctab, stab);

    attn_k<<<dim3(S_ / 128, B_ * NH_), dim3(256), 0, stream>>>(q_ws, k_ws, v_t, o_ws);

    wtrans_k<<<dim3(32, 32), dim3(256), 0, stream>>>(
        wo, 2048, wo, 0, wo, 0, woT, HID_);

    // OUT: BM=128, BN=256 -> grid 8 x 32 = 256 blocks (exactly 1/CU)
    gemm256_k<1, 128><<<dim3(8, 32), dim3(512), 0, stream>>>(
        o_ws, woT, bo, nullptr, nullptr, nullptr, nullptr, nullptr,
        (float*)d_out, nullptr, nullptr);
}

// Round 3
// 338.032 us; speedup vs baseline: 1.1819x; 1.0278x over previous
//
#include <hip/hip_runtime.h>
#include <hip/hip_bf16.h>
#include <math.h>

#define B_   2
#define S_   2048
#define HID_ 2048
#define NH_  32
#define NKV_ 8
#define D_   64
#define G_   (NH_/NKV_)
#define M_   (B_*S_)      // 4096

typedef __hip_bfloat16 bf16;
typedef short bf16x8 __attribute__((ext_vector_type(8)));
typedef float f32x4  __attribute__((ext_vector_type(4)));
typedef unsigned short u16x4 __attribute__((ext_vector_type(4)));

__device__ inline unsigned short f2bfu(float f){
    __hip_bfloat16 h = __float2bfloat16(f);
    return __builtin_bit_cast(unsigned short, h);
}

__device__ __forceinline__ float fexp2(float x){
#if __has_builtin(__builtin_amdgcn_exp2f)
    return __builtin_amdgcn_exp2f(x);
#else
    return exp2f(x);
#endif
}

// async global->LDS, 16B per lane. LDS dest = wave-uniform base + lane*16.
__device__ __forceinline__ void async16(const void* g, void* l) {
    __builtin_amdgcn_global_load_lds(
        (const __attribute__((address_space(1))) unsigned int*)g,
        (__attribute__((address_space(3))) unsigned int*)l, 16, 0, 0);
}

// XOR swizzle for 128B (64 ushort) rows (attn): spreads 16B slots across banks.
#define SWZ(r, c) ((c) ^ (((r) & 7) << 3))

// raw barrier + counted waitcnt
#define S_BARRIER() asm volatile("s_barrier" ::: "memory")
__device__ __forceinline__ void vmwait4(){ asm volatile("s_waitcnt vmcnt(4)" ::: "memory"); }
__device__ __forceinline__ void vmwait0(){ asm volatile("s_waitcnt vmcnt(0)" ::: "memory"); }

// ---------------------------------------------------------------------------
// fp32 -> bf16 bulk convert (8 elems/thread)
// ---------------------------------------------------------------------------
__global__ __launch_bounds__(256) void cvt_k(
    const float* __restrict__ src, bf16* __restrict__ dst, int n)
{
    const int i = (blockIdx.x * 256 + threadIdx.x) * 8;
    if (i >= n) return;
    const float4 a = *(const float4*)(src + i);
    const float4 b = *(const float4*)(src + i + 4);
    uint4 u;
    u.x = (unsigned)f2bfu(a.x) | ((unsigned)f2bfu(a.y) << 16);
    u.y = (unsigned)f2bfu(a.z) | ((unsigned)f2bfu(a.w) << 16);
    u.z = (unsigned)f2bfu(b.x) | ((unsigned)f2bfu(b.y) << 16);
    u.w = (unsigned)f2bfu(b.z) | ((unsigned)f2bfu(b.w) << 16);
    *(uint4*)((unsigned short*)dst + i) = u;
}

// ---------------------------------------------------------------------------
// Transpose + convert: dst[n][k] (bf16) = src_seg[k][n] (fp32).
// ---------------------------------------------------------------------------
__global__ __launch_bounds__(256) void wtrans_k(
    const float* __restrict__ s0, int N0,
    const float* __restrict__ s1, int N1,
    const float* __restrict__ s2, int N2,
    bf16* __restrict__ dst, int K)
{
    __shared__ unsigned short t[64][65];
    const int ntile = blockIdx.x * 64, ktile = blockIdx.y * 64;
    const float* src; int nloc, Nseg;
    if (ntile < N0)           { src = s0; nloc = ntile;           Nseg = N0; }
    else if (ntile < N0 + N1) { src = s1; nloc = ntile - N0;      Nseg = N1; }
    else                      { src = s2; nloc = ntile - N0 - N1; Nseg = N2; }
    const int r  = threadIdx.x >> 4;
    const int c4 = (threadIdx.x & 15) * 4;
    #pragma unroll
    for (int p = 0; p < 4; p++) {
        const int k = p * 16 + r;
        const float4 f = *(const float4*)(src + (size_t)(ktile + k) * Nseg + nloc + c4);
        t[k][c4+0] = f2bfu(f.x); t[k][c4+1] = f2bfu(f.y);
        t[k][c4+2] = f2bfu(f.z); t[k][c4+3] = f2bfu(f.w);
    }
    __syncthreads();
    #pragma unroll
    for (int p = 0; p < 4; p++) {
        const int n = p * 16 + r;
        u16x4 u = { t[c4+0][n], t[c4+1][n], t[c4+2][n], t[c4+3][n] };
        *(u16x4*)((unsigned short*)dst + (size_t)(ntile + n) * K + ktile + c4) = u;
    }
}

// ---------------------------------------------------------------------------
// RoPE cos/sin table (double precision); int32/int64 position_ids handled.
// ---------------------------------------------------------------------------
__global__ __launch_bounds__(256) void rope_tab_k(
    const int* __restrict__ pos, float* __restrict__ ctab, float* __restrict__ stab)
{
    const int idx = blockIdx.x * 256 + threadIdx.x;
    if (idx >= S_ * 32) return;
    const int s = idx >> 5, i = idx & 31;
    const int is64 = (pos[1] == 0);
    const int p = is64 ? pos[2 * s] : pos[s];
    const double inv = exp(-(double)i * (log(150000.0) / 32.0));
    const double f = (double)p * inv;
    ctab[idx] = (float)cos(f);
    stab[idx] = (float)sin(f);
}

// ---------------------------------------------------------------------------
// 8-phase pipelined MFMA GEMM (m201-style): C = A[M,2048] @ WT[N,2048]^T.
// BM x 256 tile, BK=64, 8 waves (2M x 4N), double-buffered LDS.
// Per iteration = 2 K-tiles = 8 phases; each phase:
//   {ds-read quadrant frags | issue one half-tile stage (2 gload_lds) |
//    s_barrier | 16 MFMA (setprio) | s_barrier}
// Counted vmcnt(4) only at end of ph3/ph7, BEFORE the closing barrier
// (barrier publishes cross-wave staging completion). Half-tile birth/death:
//   buf B-halves die after the tile's ph0 (B-frags are register-cached),
//   A-halves after ph3. Stage slots: ph0-1 A(T+1)->buf1, ph2-3 B(T+2)->buf0,
//   ph4-5 A(T+2)->buf0, ph6-7 B(T+3)->buf1. Leftover after each vmcnt(4) is
//   exactly the newest B-half pair. Tail stages wrap into dead regions.
// MODE 0: QKV epilogue (Q: RoPE + 0.125*log2e; K: RoPE; V: transposed store).
// MODE 1: OUT epilogue (fp32 + bias b0), BM=128.
// ---------------------------------------------------------------------------

// stage 64 rows (one slab) of a [rows x 2048] bf16 matrix into LDS (linear),
// global source chunk pre-swizzled so the ds_read side can XOR-deswizzle.
__device__ __forceinline__ void slab64(
    const bf16* __restrict__ g, int grow0, int k0,
    unsigned short* lds, int wave, int lane)
{
    const int rr = wave * 8 + (lane >> 3);
    const int cc = ((lane & 7) ^ (lane >> 3)) * 8;
    async16(g + (size_t)(grow0 + rr) * 2048 + k0 + cc, lds + wave * 512);
}

template<int MODE, int BM>
__global__ __launch_bounds__(512, 2) void gemm8p_k(
    const bf16* __restrict__ A, const bf16* __restrict__ WT,
    const float* __restrict__ b0, const float* __restrict__ b1,
    const float* __restrict__ b2,
    bf16* __restrict__ Cq, bf16* __restrict__ Ck, bf16* __restrict__ Cv,
    float* __restrict__ Cout,
    const float* __restrict__ ctab, const float* __restrict__ stab)
{
    constexpr int MT = BM / 32;    // m-frags per wave
    constexpr int PM = MT / 4;     // m-frags per phase (quadrant)
    constexpr int LA = BM * 64;    // ushorts per A buffer
    constexpr int LB = 256 * 64;   // ushorts per B buffer
    constexpr int NT = 32;         // K-tiles (2048/64)
    __shared__ unsigned short sA[2 * LA];
    __shared__ unsigned short sB[2 * LB];

    const int tid  = threadIdx.x;
    const int wave = tid >> 6, lane = tid & 63;
    const int li   = lane & 15, lj = lane >> 4;
    const int wm   = wave >> 2, wn = wave & 3;
    const int m0   = blockIdx.y * BM;
    const int n0   = blockIdx.x * 256;
    const int swz  = li & 7;

    f32x4 acc[MT][4];
    #pragma unroll
    for (int i = 0; i < MT; ++i)
        #pragma unroll
        for (int j = 0; j < 4; ++j)
            acc[i][j] = (f32x4){0.f, 0.f, 0.f, 0.f};

    bf16x8 bfr[4][2];

    // stage half-tile (128 rows) of A / B for tile t (wraps past NT harmlessly)
    auto stageA = [&](int t, int r0) {
        unsigned short* l = sA + (t & 1) * LA + r0 * 64;
        const int k0 = (t & (NT - 1)) * 64;
        slab64(A, m0 + r0,      k0, l,            wave, lane);
        slab64(A, m0 + r0 + 64, k0, l + 64 * 64,  wave, lane);
    };
    auto stageB = [&](int t, int r0) {
        unsigned short* l = sB + (t & 1) * LB + r0 * 64;
        const int k0 = (t & (NT - 1)) * 64;
        slab64(WT, n0 + r0,      k0, l,           wave, lane);
        slab64(WT, n0 + r0 + 64, k0, l + 64 * 64, wave, lane);
    };
    auto ldB = [&](int tb) {
        const unsigned short* base = sB + tb * LB;
        #pragma unroll
        for (int nt = 0; nt < 4; ++nt)
            #pragma unroll
            for (int ks = 0; ks < 2; ++ks)
                bfr[nt][ks] = *(const bf16x8*)
                    &base[(wn * 64 + nt * 16 + li) * 64 + ((ks * 4 + lj) ^ swz) * 8];
    };
    auto ldA = [&](int tb, int q, bf16x8 (*af)[2]) {
        const unsigned short* base = sA + tb * LA;
        #pragma unroll
        for (int m = 0; m < PM; ++m)
            #pragma unroll
            for (int ks = 0; ks < 2; ++ks)
                af[m][ks] = *(const bf16x8*)
                    &base[(wm * (BM / 2) + (q * PM + m) * 16 + li) * 64
                          + ((ks * 4 + lj) ^ swz) * 8];
    };
    auto mfma_q = [&](int q, bf16x8 (*af)[2]) {
        __builtin_amdgcn_s_setprio(1);
        #pragma unroll
        for (int ks = 0; ks < 2; ++ks)
            #pragma unroll
            for (int m = 0; m < PM; ++m)
                #pragma unroll
                for (int nt = 0; nt < 4; ++nt)
                    acc[q * PM + m][nt] = __builtin_amdgcn_mfma_f32_16x16x32_bf16(
                        af[m][ks], bfr[nt][ks], acc[q * PM + m][nt], 0, 0, 0);
        __builtin_amdgcn_s_setprio(0);
    };

    // prologue: tile 0 (A+B) + B(1); vmcnt(4) leaves B(1) in flight.
    stageA(0, 0);
    if constexpr (BM == 256) stageA(0, 128);
    stageB(0, 0); stageB(0, 128);
    stageB(1, 0); stageB(1, 128);
    vmwait4();
    S_BARRIER();

    for (int i = 0; i < NT / 2; ++i) {
        const int ta = 2 * i, tb = 2 * i + 1;
        bf16x8 af0[PM][2], af1[PM][2], af2[PM][2], af3[PM][2];
        // ---- tile ta (buf0) ----
        ldB(0); ldA(0, 0, af0);
        stageA(tb, 0);                                   // A(T+1) half 0 -> buf1
        S_BARRIER(); mfma_q(0, af0); S_BARRIER();
        ldA(0, 1, af1);
        if constexpr (BM == 256) stageA(tb, 128);        // A(T+1) half 1
        S_BARRIER(); mfma_q(1, af1); S_BARRIER();
        ldA(0, 2, af2);
        stageB(ta + 2, 0);                               // B(T+2) half 0 -> buf0
        S_BARRIER(); mfma_q(2, af2); S_BARRIER();
        ldA(0, 3, af3);
        stageB(ta + 2, 128);                             // B(T+2) half 1
        S_BARRIER(); mfma_q(3, af3);
        vmwait4();                                        // A(T+1),B(T+1) landed
        S_BARRIER();
        // ---- tile tb (buf1) ----
        ldB(1); ldA(1, 0, af0);
        stageA(ta + 2, 0);                               // A(T+2) half 0 -> buf0
        S_BARRIER(); mfma_q(0, af0); S_BARRIER();
        ldA(1, 1, af1);
        if constexpr (BM == 256) stageA(ta + 2, 128);    // A(T+2) half 1
        S_BARRIER(); mfma_q(1, af1); S_BARRIER();
        ldA(1, 2, af2);
        stageB(tb + 2, 0);                               // B(T+3) half 0 -> buf1
        S_BARRIER(); mfma_q(2, af2); S_BARRIER();
        ldA(1, 3, af3);
        stageB(tb + 2, 128);                             // B(T+3) half 1
        S_BARRIER(); mfma_q(3, af3);
        vmwait4();                                        // A(T+2),B(T+2) landed
        S_BARRIER();
    }
    vmwait0();
    S_BARRIER();

    // ------------------------------ epilogue ------------------------------
    if (MODE == 1) {
        #pragma unroll
        for (int mt = 0; mt < MT; ++mt)
            #pragma unroll
            for (int nt = 0; nt < 4; ++nt) {
                const int col = n0 + wn * 64 + nt * 16 + li;
                const float bb = b0[col];
                #pragma unroll
                for (int r = 0; r < 4; ++r) {
                    const int row = m0 + wm * (BM / 2) + mt * 16 + lj * 4 + r;
                    Cout[(size_t)row * HID_ + col] = acc[mt][nt][r] + bb;
                }
            }
        return;
    }

    int seg, cb; const float* bias;
    if (n0 < 2048)      { seg = 0; cb = n0;        bias = b0; }
    else if (n0 < 2560) { seg = 1; cb = n0 - 2048; bias = b1; }
    else                { seg = 2; cb = n0 - 2560; bias = b2; }

    float bl[4];
    #pragma unroll
    for (int nt = 0; nt < 4; ++nt) bl[nt] = bias[cb + wn * 64 + nt * 16 + li];

    if (seg == 2) {
        const int b = m0 >> 11;
        #pragma unroll
        for (int nt = 0; nt < 4; ++nt) {
            const int cseg = cb + wn * 64 + nt * 16 + li;
            const int hv = cseg >> 6, d = cseg & 63;
            #pragma unroll
            for (int mt = 0; mt < MT; ++mt) {
                const int sb = (m0 & (S_ - 1)) + wm * (BM / 2) + mt * 16 + lj * 4;
                u16x4 u = { f2bfu(acc[mt][nt][0] + bl[nt]),
                            f2bfu(acc[mt][nt][1] + bl[nt]),
                            f2bfu(acc[mt][nt][2] + bl[nt]),
                            f2bfu(acc[mt][nt][3] + bl[nt]) };
                *(u16x4*)((unsigned short*)Cv +
                    ((size_t)((b * NKV_ + hv) * 64 + d)) * S_ + sb) = u;
            }
        }
        return;
    }

    // Q/K: fused RoPE. Q also folds 0.125 * log2(e) (exp2-domain softmax).
    const float qs = (seg == 0) ? 0.18033688011112042f : 1.0f;
    #pragma unroll
    for (int mt = 0; mt < MT; ++mt) {
        #pragma unroll
        for (int r = 0; r < 4; ++r) {
            const int row = m0 + wm * (BM / 2) + mt * 16 + lj * 4 + r;
            const int s = row & (S_ - 1);
            const float c0  = ctab[s * 32 + li],      sn0 = stab[s * 32 + li];
            const float c1  = ctab[s * 32 + 16 + li], sn1 = stab[s * 32 + 16 + li];
            const float x0 = acc[mt][0][r] + bl[0];
            const float x1 = acc[mt][1][r] + bl[1];
            const float x2 = acc[mt][2][r] + bl[2];
            const float x3 = acc[mt][3][r] + bl[3];
            const float y0 = (x0 * c0 - x2 * sn0) * qs;
            const float y2 = (x2 * c0 + x0 * sn0) * qs;
            const float y1 = (x1 * c1 - x3 * sn1) * qs;
            const float y3 = (x3 * c1 + x1 * sn1) * qs;
            if (seg == 0) {
                bf16* cp = Cq + (size_t)row * HID_ + n0 + wn * 64 + li;
                cp[0]  = __float2bfloat16(y0);
                cp[16] = __float2bfloat16(y1);
                cp[32] = __float2bfloat16(y2);
                cp[48] = __float2bfloat16(y3);
            } else {
                bf16* cp = Ck + (size_t)row * 512 + cb + wn * 64 + li;
                cp[0]  = __float2bfloat16(y0);
                cp[16] = __float2bfloat16(y1);
                cp[32] = __float2bfloat16(y2);
                cp[48] = __float2bfloat16(y3);
            }
        }
    }
}

// ---------------------------------------------------------------------------
// MFMA flash attention (unchanged — verified at ~115 us).
// ---------------------------------------------------------------------------
__global__ __launch_bounds__(256, 4) void attn_k(
    const bf16* __restrict__ qws, const bf16* __restrict__ kws,
    const bf16* __restrict__ vtw, bf16* __restrict__ ows)
{
    __shared__ unsigned short sK [64 * 64];     // [key][dim], swizzled
    __shared__ unsigned short sVt[64 * 64];     // [dim][key], swizzled
    __shared__ unsigned short sP [4 * 32 * 64]; // per-wave [2*16 q][key], swizzled

    const int tid  = threadIdx.x;
    const int wave = tid >> 6, lane = tid & 63;
    const int li   = lane & 15, lj = lane >> 4;
    const int bh   = blockIdx.y;
    const int q0   = blockIdx.x * 128;
    const int b    = bh / NH_, h = bh % NH_;
    const int hk   = h / G_;

    bf16x8 qf[2][2];
    #pragma unroll
    for (int g = 0; g < 2; g++) {
        const bf16* qp = qws + (size_t)(b * S_ + q0 + wave * 32 + g * 16 + li) * HID_
                         + h * D_ + lj * 8;
        qf[g][0] = *(const bf16x8*)(qp);
        qf[g][1] = *(const bf16x8*)(qp + 32);
    }

    f32x4 o[2][4];
    #pragma unroll
    for (int g = 0; g < 2; g++)
        #pragma unroll
        for (int mt = 0; mt < 4; mt++) o[g][mt] = (f32x4){0.f, 0.f, 0.f, 0.f};
    float mr[2] = {-1e30f, -1e30f};
    float ll[2] = {0.f, 0.f};

    const int srow = tid >> 2, scol = (tid & 3) * 16;
    const bf16* kb = kws + (size_t)b * S_ * 512 + hk * 64;
    const bf16* vb = vtw + (size_t)((b * NKV_ + hk) * 64) * S_;
    unsigned short* sp = sP + wave * (32 * 64);

    uint4 pk0, pk1, pv0, pv1;
    {
        const uint4* kp = (const uint4*)(kb + (size_t)srow * 512 + scol);
        const uint4* vp = (const uint4*)(vb + (size_t)srow * S_ + scol);
        pk0 = kp[0]; pk1 = kp[1]; pv0 = vp[0]; pv1 = vp[1];
    }

    for (int kt = 0; kt < S_; kt += 64) {
        __syncthreads();
        *(uint4*)&sK [srow * 64 + SWZ(srow, scol)]     = pk0;
        *(uint4*)&sK [srow * 64 + SWZ(srow, scol + 8)] = pk1;
        *(uint4*)&sVt[srow * 64 + SWZ(srow, scol)]     = pv0;
        *(uint4*)&sVt[srow * 64 + SWZ(srow, scol + 8)] = pv1;
        __syncthreads();

        if (kt + 64 < S_) {
            const uint4* kp = (const uint4*)(kb + (size_t)(kt + 64 + srow) * 512 + scol);
            const uint4* vp = (const uint4*)(vb + (size_t)srow * S_ + kt + 64 + scol);
            pk0 = kp[0]; pk1 = kp[1]; pv0 = vp[0]; pv1 = vp[1];
        }

        float sc[2][4][4];
        __builtin_amdgcn_s_setprio(1);
        #pragma unroll
        for (int nt = 0; nt < 4; nt++) {
            f32x4 c0 = (f32x4){0.f, 0.f, 0.f, 0.f};
            f32x4 c1 = (f32x4){0.f, 0.f, 0.f, 0.f};
            #pragma unroll
            for (int ks = 0; ks < 2; ks++) {
                const bf16x8 kf =
                    *(const bf16x8*)&sK[(nt * 16 + li) * 64 + SWZ(li, ks * 32 + lj * 8)];
                c0 = __builtin_amdgcn_mfma_f32_16x16x32_bf16(kf, qf[0][ks], c0, 0, 0, 0);
                c1 = __builtin_amdgcn_mfma_f32_16x16x32_bf16(kf, qf[1][ks], c1, 0, 0, 0);
            }
            #pragma unroll
            for (int r = 0; r < 4; r++) { sc[0][nt][r] = c0[r]; sc[1][nt][r] = c1[r]; }
        }
        __builtin_amdgcn_s_setprio(0);

        #pragma unroll
        for (int g = 0; g < 2; g++) {
            float cm = sc[g][0][0];
            #pragma unroll
            for (int nt = 0; nt < 4; nt++)
                #pragma unroll
                for (int r = 0; r < 4; r++) cm = fmaxf(cm, sc[g][nt][r]);
            cm = fmaxf(cm, __shfl_xor(cm, 16));
            cm = fmaxf(cm, __shfl_xor(cm, 32));
            if (!__all(cm - mr[g] <= 8.0f)) {
                const float mnew = fmaxf(mr[g], cm);
                const float al   = fexp2(mr[g] - mnew);
                mr[g] = mnew;
                ll[g] *= al;
                #pragma unroll
                for (int mt = 0; mt < 4; mt++) o[g][mt] *= al;
            }
            float rs = 0.f;
            #pragma unroll
            for (int nt = 0; nt < 4; nt++) {
                const float e0 = fexp2(sc[g][nt][0] - mr[g]);
                const float e1 = fexp2(sc[g][nt][1] - mr[g]);
                const float e2 = fexp2(sc[g][nt][2] - mr[g]);
                const float e3 = fexp2(sc[g][nt][3] - mr[g]);
                rs += (e0 + e1) + (e2 + e3);
                u16x4 u = { f2bfu(e0), f2bfu(e1), f2bfu(e2), f2bfu(e3) };
                *(u16x4*)&sp[(g * 16 + li) * 64 + SWZ(li, nt * 16 + lj * 4)] = u;
            }
            ll[g] += rs;
        }

        __builtin_amdgcn_s_setprio(1);
        #pragma unroll
        for (int ks = 0; ks < 2; ks++) {
            const bf16x8 pf0 = *(const bf16x8*)&sp[(li)      * 64 + SWZ(li, ks * 32 + lj * 8)];
            const bf16x8 pf1 = *(const bf16x8*)&sp[(16 + li) * 64 + SWZ(li, ks * 32 + lj * 8)];
            #pragma unroll
            for (int mt = 0; mt < 4; mt++) {
                const bf16x8 vf =
                    *(const bf16x8*)&sVt[(mt * 16 + li) * 64 + SWZ(li, ks * 32 + lj * 8)];
                o[0][mt] = __builtin_amdgcn_mfma_f32_16x16x32_bf16(vf, pf0, o[0][mt], 0, 0, 0);
                o[1][mt] = __builtin_amdgcn_mfma_f32_16x16x32_bf16(vf, pf1, o[1][mt], 0, 0, 0);
            }
        }
        __builtin_amdgcn_s_setprio(0);
    }

    #pragma unroll
    for (int g = 0; g < 2; g++) {
        float l = ll[g];
        l += __shfl_xor(l, 16);
        l += __shfl_xor(l, 32);
        const float inv = 1.0f / l;
        bf16* op = ows + (size_t)(b * S_ + q0 + wave * 32 + g * 16 + li) * HID_ + h * D_;
        #pragma unroll
        for (int mt = 0; mt < 4; mt++) {
            u16x4 u = { f2bfu(o[g][mt][0] * inv), f2bfu(o[g][mt][1] * inv),
                        f2bfu(o[g][mt][2] * inv), f2bfu(o[g][mt][3] * inv) };
            *(u16x4*)((unsigned short*)op + mt * 16 + lj * 4) = u;
        }
    }
}

// ---------------------------------------------------------------------------
extern "C" void kernel_launch(void* const* d_in, const int* in_sizes, int n_in,
                              void* d_out, int out_size, void* d_ws, size_t ws_size,
                              hipStream_t stream)
{
    const float* hs  = (const float*)d_in[0];
    const int*   pos = (const int*)d_in[1];
    const float* wq = (const float*)d_in[2];
    const float* bq = (const float*)d_in[3];
    const float* wk = (const float*)d_in[4];
    const float* bk = (const float*)d_in[5];
    const float* wv = (const float*)d_in[6];
    const float* bv = (const float*)d_in[7];
    const float* wo = (const float*)d_in[8];
    const float* bo = (const float*)d_in[9];

    // workspace (52.5 MB peak)
    char* ws = (char*)d_ws;
    float* ctab  = (float*)(ws);
    float* stab  = (float*)(ws + (256u << 10));
    bf16*  k_ws  = (bf16*)(ws + (512u << 10));
    bf16*  v_t   = (bf16*)(ws + (512u << 10) + (4u  << 20));
    bf16*  q_ws  = (bf16*)(ws + (512u << 10) + (8u  << 20));
    bf16*  woT   = q_ws;                                   // overlay
    bf16*  hs_b  = (bf16*)(ws + (512u << 10) + (24u << 20));
    bf16*  o_ws  = hs_b;                                   // overlay
    bf16*  wqkvT = (bf16*)(ws + (512u << 10) + (40u << 20));

    rope_tab_k<<<dim3(256), dim3(256), 0, stream>>>(pos, ctab, stab);

    cvt_k<<<dim3(M_ * HID_ / 2048), dim3(256), 0, stream>>>(hs, hs_b, M_ * HID_);

    wtrans_k<<<dim3(48, 32), dim3(256), 0, stream>>>(
        wq, 2048, wk, 512, wv, 512, wqkvT, HID_);

    // QKV: BM=256, BN=256 -> grid 12 x 16 = 192 blocks
    gemm8p_k<0, 256><<<dim3(12, 16), dim3(512), 0, stream>>>(
        hs_b, wqkvT, bq, bk, bv, q_ws, k_ws, v_t, nullptr, ctab, stab);

    attn_k<<<dim3(S_ / 128, B_ * NH_), dim3(256), 0, stream>>>(q_ws, k_ws, v_t, o_ws);

    wtrans_k<<<dim3(32, 32), dim3(256), 0, stream>>>(
        wo, 2048, wo, 0, wo, 0, woT, HID_);

    // OUT: BM=128, BN=256 -> grid 8 x 32 = 256 blocks (exactly 1/CU)
    gemm8p_k<1, 128><<<dim3(8, 32), dim3(512), 0, stream>>>(
        o_ws, woT, bo, nullptr, nullptr, nullptr, nullptr, nullptr,
        (float*)d_out, nullptr, nullptr);
}

// Round 4
// 325.005 us; speedup vs baseline: 1.2293x; 1.0401x over previous
//
#include <hip/hip_runtime.h>
#include <hip/hip_bf16.h>
#include <math.h>

#define B_   2
#define S_   2048
#define HID_ 2048
#define NH_  32
#define NKV_ 8
#define D_   64
#define G_   (NH_/NKV_)
#define M_   (B_*S_)      // 4096

typedef __hip_bfloat16 bf16;
typedef short bf16x8 __attribute__((ext_vector_type(8)));
typedef float f32x4  __attribute__((ext_vector_type(4)));
typedef unsigned short u16x4 __attribute__((ext_vector_type(4)));

__device__ inline unsigned short f2bfu(float f){
    __hip_bfloat16 h = __float2bfloat16(f);
    return __builtin_bit_cast(unsigned short, h);
}

__device__ __forceinline__ float fexp2(float x){
#if __has_builtin(__builtin_amdgcn_exp2f)
    return __builtin_amdgcn_exp2f(x);
#else
    return exp2f(x);
#endif
}

// async global->LDS, 16B per lane. LDS dest = wave-uniform base + lane*16.
__device__ __forceinline__ void async16(const void* g, void* l) {
    __builtin_amdgcn_global_load_lds(
        (const __attribute__((address_space(1))) unsigned int*)g,
        (__attribute__((address_space(3))) unsigned int*)l, 16, 0, 0);
}

// XOR swizzle for 128B (64 ushort) rows (attn): spreads 16B slots across banks.
#define SWZ(r, c) ((c) ^ (((r) & 7) << 3))

// raw barrier + counted waitcnt
#define S_BARRIER() asm volatile("s_barrier" ::: "memory")
__device__ __forceinline__ void vmwait4(){ asm volatile("s_waitcnt vmcnt(4)" ::: "memory"); }
__device__ __forceinline__ void vmwait0(){ asm volatile("s_waitcnt vmcnt(0)" ::: "memory"); }

// ---------------------------------------------------------------------------
// Transpose + convert body: dst[n][k] (bf16) = src_seg[k][n] (fp32).
// tbuf must hold >= 64*65 ushorts of LDS.
// ---------------------------------------------------------------------------
__device__ __forceinline__ void wtrans_body(
    const float* __restrict__ s0, int N0,
    const float* __restrict__ s1, int N1,
    const float* __restrict__ s2, int N2,
    bf16* __restrict__ dst, int K, int bx, int by,
    unsigned short* __restrict__ tbuf)
{
    unsigned short (*t)[65] = (unsigned short (*)[65])tbuf;
    const int ntile = bx * 64, ktile = by * 64;
    const float* src; int nloc, Nseg;
    if (ntile < N0)           { src = s0; nloc = ntile;           Nseg = N0; }
    else if (ntile < N0 + N1) { src = s1; nloc = ntile - N0;      Nseg = N1; }
    else                      { src = s2; nloc = ntile - N0 - N1; Nseg = N2; }
    const int r  = threadIdx.x >> 4;
    const int c4 = (threadIdx.x & 15) * 4;
    #pragma unroll
    for (int p = 0; p < 4; p++) {
        const int k = p * 16 + r;
        const float4 f = *(const float4*)(src + (size_t)(ktile + k) * Nseg + nloc + c4);
        t[k][c4+0] = f2bfu(f.x); t[k][c4+1] = f2bfu(f.y);
        t[k][c4+2] = f2bfu(f.z); t[k][c4+3] = f2bfu(f.w);
    }
    __syncthreads();
    #pragma unroll
    for (int p = 0; p < 4; p++) {
        const int n = p * 16 + r;
        u16x4 u = { t[c4+0][n], t[c4+1][n], t[c4+2][n], t[c4+3][n] };
        *(u16x4*)((unsigned short*)dst + (size_t)(ntile + n) * K + ktile + c4) = u;
    }
}

// ---------------------------------------------------------------------------
// Fused prep: blocks [0,4096) fp32->bf16 convert of hidden_states;
//             [4096,5632) wtrans of wq|wk|wv -> wqkvT;
//             [5632,5888) RoPE cos/sin tables.
// ---------------------------------------------------------------------------
__global__ __launch_bounds__(256) void prep_k(
    const float* __restrict__ hs, bf16* __restrict__ hs_b,
    const float* __restrict__ wq, const float* __restrict__ wk,
    const float* __restrict__ wv, bf16* __restrict__ wqkvT,
    const int* __restrict__ pos, float* __restrict__ ctab,
    float* __restrict__ stab)
{
    __shared__ unsigned short tbuf[64 * 65];
    const int bid = blockIdx.x;
    if (bid < 4096) {
        const int i = (bid * 256 + threadIdx.x) * 8;
        const float4 a = *(const float4*)(hs + i);
        const float4 b = *(const float4*)(hs + i + 4);
        uint4 u;
        u.x = (unsigned)f2bfu(a.x) | ((unsigned)f2bfu(a.y) << 16);
        u.y = (unsigned)f2bfu(a.z) | ((unsigned)f2bfu(a.w) << 16);
        u.z = (unsigned)f2bfu(b.x) | ((unsigned)f2bfu(b.y) << 16);
        u.w = (unsigned)f2bfu(b.z) | ((unsigned)f2bfu(b.w) << 16);
        *(uint4*)((unsigned short*)hs_b + i) = u;
    } else if (bid < 5632) {
        const int t = bid - 4096;                       // 0..1535 (48 x 32)
        wtrans_body(wq, 2048, wk, 512, wv, 512, wqkvT, HID_,
                    t % 48, t / 48, tbuf);
    } else {
        const int idx = (bid - 5632) * 256 + threadIdx.x;
        const int s = idx >> 5, i = idx & 31;
        const int is64 = (pos[1] == 0);
        const int p = is64 ? pos[2 * s] : pos[s];
        const double inv = exp(-(double)i * (log(150000.0) / 32.0));
        const double f = (double)p * inv;
        ctab[idx] = (float)cos(f);
        stab[idx] = (float)sin(f);
    }
}

// ---------------------------------------------------------------------------
// 8-phase pipelined MFMA GEMM (m201-style): C = A[M,2048] @ WT[N,2048]^T.
// BM x 256 tile, BK=64, 8 waves (2M x 4N), double-buffered LDS.
// Counted vmcnt(4) only twice per 2-tile iteration; XOR chunk swizzle
// both-sides (pre-swizzled global source -> linear gload_lds; swizzled
// ds_read). T1: XCD-chunked block remap (grid %8 == 0), m-fastest within
// an XCD so co-located blocks share B panels in that XCD's L2.
// MODE 0: QKV epilogue (Q: RoPE + 0.125*log2e; K: RoPE; V: transposed store).
// MODE 1: OUT epilogue (fp32 + bias b0), BM=128.
// ---------------------------------------------------------------------------
__device__ __forceinline__ void slab64(
    const bf16* __restrict__ g, int grow0, int k0,
    unsigned short* lds, int wave, int lane)
{
    const int rr = wave * 8 + (lane >> 3);
    const int cc = ((lane & 7) ^ (lane >> 3)) * 8;
    async16(g + (size_t)(grow0 + rr) * 2048 + k0 + cc, lds + wave * 512);
}

template<int MODE, int BM>
__global__ __launch_bounds__(512, 2) void gemm8p_k(
    const bf16* __restrict__ A, const bf16* __restrict__ WT,
    const float* __restrict__ b0, const float* __restrict__ b1,
    const float* __restrict__ b2,
    bf16* __restrict__ Cq, bf16* __restrict__ Ck, bf16* __restrict__ Cv,
    float* __restrict__ Cout,
    const float* __restrict__ ctab, const float* __restrict__ stab)
{
    constexpr int MT = BM / 32;    // m-frags per wave
    constexpr int PM = MT / 4;     // m-frags per phase (quadrant)
    constexpr int LA = BM * 64;    // ushorts per A buffer
    constexpr int LB = 256 * 64;   // ushorts per B buffer
    constexpr int NT = 32;         // K-tiles (2048/64)
    __shared__ unsigned short sA[2 * LA];
    __shared__ unsigned short sB[2 * LB];

    const int tid  = threadIdx.x;
    const int wave = tid >> 6, lane = tid & 63;
    const int li   = lane & 15, lj = lane >> 4;
    const int wm   = wave >> 2, wn = wave & 3;

    // T1: XCD-chunked bijective remap (nwg % 8 == 0 for both instantiations).
    const int nbx = gridDim.x, nby = gridDim.y;
    const int lin = blockIdx.y * nbx + blockIdx.x;
    const int qq  = (nbx * nby) >> 3;
    const int logical = (lin & 7) * qq + (lin >> 3);
    const int m0 = (logical % nby) * BM;
    const int n0 = (logical / nby) * 256;
    const int swz = li & 7;

    f32x4 acc[MT][4];
    #pragma unroll
    for (int i = 0; i < MT; ++i)
        #pragma unroll
        for (int j = 0; j < 4; ++j)
            acc[i][j] = (f32x4){0.f, 0.f, 0.f, 0.f};

    bf16x8 bfr[4][2];

    auto stageA = [&](int t, int r0) {
        unsigned short* l = sA + (t & 1) * LA + r0 * 64;
        const int k0 = (t & (NT - 1)) * 64;
        slab64(A, m0 + r0,      k0, l,           wave, lane);
        slab64(A, m0 + r0 + 64, k0, l + 64 * 64, wave, lane);
    };
    auto stageB = [&](int t, int r0) {
        unsigned short* l = sB + (t & 1) * LB + r0 * 64;
        const int k0 = (t & (NT - 1)) * 64;
        slab64(WT, n0 + r0,      k0, l,           wave, lane);
        slab64(WT, n0 + r0 + 64, k0, l + 64 * 64, wave, lane);
    };
    auto ldB = [&](int tb) {
        const unsigned short* base = sB + tb * LB;
        #pragma unroll
        for (int nt = 0; nt < 4; ++nt)
            #pragma unroll
            for (int ks = 0; ks < 2; ++ks)
                bfr[nt][ks] = *(const bf16x8*)
                    &base[(wn * 64 + nt * 16 + li) * 64 + ((ks * 4 + lj) ^ swz) * 8];
    };
    auto ldA = [&](int tb, int q, bf16x8 (*af)[2]) {
        const unsigned short* base = sA + tb * LA;
        #pragma unroll
        for (int m = 0; m < PM; ++m)
            #pragma unroll
            for (int ks = 0; ks < 2; ++ks)
                af[m][ks] = *(const bf16x8*)
                    &base[(wm * (BM / 2) + (q * PM + m) * 16 + li) * 64
                          + ((ks * 4 + lj) ^ swz) * 8];
    };
    auto mfma_q = [&](int q, bf16x8 (*af)[2]) {
        __builtin_amdgcn_s_setprio(1);
        #pragma unroll
        for (int ks = 0; ks < 2; ++ks)
            #pragma unroll
            for (int m = 0; m < PM; ++m)
                #pragma unroll
                for (int nt = 0; nt < 4; ++nt)
                    acc[q * PM + m][nt] = __builtin_amdgcn_mfma_f32_16x16x32_bf16(
                        af[m][ks], bfr[nt][ks], acc[q * PM + m][nt], 0, 0, 0);
        __builtin_amdgcn_s_setprio(0);
    };

    // prologue: tile 0 (A+B) + B(1); vmcnt(4) leaves B(1) in flight.
    stageA(0, 0);
    if constexpr (BM == 256) stageA(0, 128);
    stageB(0, 0); stageB(0, 128);
    stageB(1, 0); stageB(1, 128);
    vmwait4();
    S_BARRIER();

    for (int i = 0; i < NT / 2; ++i) {
        const int ta = 2 * i, tb = 2 * i + 1;
        bf16x8 af0[PM][2], af1[PM][2], af2[PM][2], af3[PM][2];
        // ---- tile ta (buf0) ----
        ldB(0); ldA(0, 0, af0);
        stageA(tb, 0);
        S_BARRIER(); mfma_q(0, af0); S_BARRIER();
        ldA(0, 1, af1);
        if constexpr (BM == 256) stageA(tb, 128);
        S_BARRIER(); mfma_q(1, af1); S_BARRIER();
        ldA(0, 2, af2);
        stageB(ta + 2, 0);
        S_BARRIER(); mfma_q(2, af2); S_BARRIER();
        ldA(0, 3, af3);
        stageB(ta + 2, 128);
        S_BARRIER(); mfma_q(3, af3);
        vmwait4();
        S_BARRIER();
        // ---- tile tb (buf1) ----
        ldB(1); ldA(1, 0, af0);
        stageA(ta + 2, 0);
        S_BARRIER(); mfma_q(0, af0); S_BARRIER();
        ldA(1, 1, af1);
        if constexpr (BM == 256) stageA(ta + 2, 128);
        S_BARRIER(); mfma_q(1, af1); S_BARRIER();
        ldA(1, 2, af2);
        stageB(tb + 2, 0);
        S_BARRIER(); mfma_q(2, af2); S_BARRIER();
        ldA(1, 3, af3);
        stageB(tb + 2, 128);
        S_BARRIER(); mfma_q(3, af3);
        vmwait4();
        S_BARRIER();
    }
    vmwait0();
    S_BARRIER();

    // ------------------------------ epilogue ------------------------------
    if (MODE == 1) {
        #pragma unroll
        for (int mt = 0; mt < MT; ++mt)
            #pragma unroll
            for (int nt = 0; nt < 4; ++nt) {
                const int col = n0 + wn * 64 + nt * 16 + li;
                const float bb = b0[col];
                #pragma unroll
                for (int r = 0; r < 4; ++r) {
                    const int row = m0 + wm * (BM / 2) + mt * 16 + lj * 4 + r;
                    Cout[(size_t)row * HID_ + col] = acc[mt][nt][r] + bb;
                }
            }
        return;
    }

    int seg, cb; const float* bias;
    if (n0 < 2048)      { seg = 0; cb = n0;        bias = b0; }
    else if (n0 < 2560) { seg = 1; cb = n0 - 2048; bias = b1; }
    else                { seg = 2; cb = n0 - 2560; bias = b2; }

    float bl[4];
    #pragma unroll
    for (int nt = 0; nt < 4; ++nt) bl[nt] = bias[cb + wn * 64 + nt * 16 + li];

    if (seg == 2) {
        const int b = m0 >> 11;
        #pragma unroll
        for (int nt = 0; nt < 4; ++nt) {
            const int cseg = cb + wn * 64 + nt * 16 + li;
            const int hv = cseg >> 6, d = cseg & 63;
            #pragma unroll
            for (int mt = 0; mt < MT; ++mt) {
                const int sb = (m0 & (S_ - 1)) + wm * (BM / 2) + mt * 16 + lj * 4;
                u16x4 u = { f2bfu(acc[mt][nt][0] + bl[nt]),
                            f2bfu(acc[mt][nt][1] + bl[nt]),
                            f2bfu(acc[mt][nt][2] + bl[nt]),
                            f2bfu(acc[mt][nt][3] + bl[nt]) };
                *(u16x4*)((unsigned short*)Cv +
                    ((size_t)((b * NKV_ + hv) * 64 + d)) * S_ + sb) = u;
            }
        }
        return;
    }

    const float qs = (seg == 0) ? 0.18033688011112042f : 1.0f;
    #pragma unroll
    for (int mt = 0; mt < MT; ++mt) {
        #pragma unroll
        for (int r = 0; r < 4; ++r) {
            const int row = m0 + wm * (BM / 2) + mt * 16 + lj * 4 + r;
            const int s = row & (S_ - 1);
            const float c0  = ctab[s * 32 + li],      sn0 = stab[s * 32 + li];
            const float c1  = ctab[s * 32 + 16 + li], sn1 = stab[s * 32 + 16 + li];
            const float x0 = acc[mt][0][r] + bl[0];
            const float x1 = acc[mt][1][r] + bl[1];
            const float x2 = acc[mt][2][r] + bl[2];
            const float x3 = acc[mt][3][r] + bl[3];
            const float y0 = (x0 * c0 - x2 * sn0) * qs;
            const float y2 = (x2 * c0 + x0 * sn0) * qs;
            const float y1 = (x1 * c1 - x3 * sn1) * qs;
            const float y3 = (x3 * c1 + x1 * sn1) * qs;
            if (seg == 0) {
                bf16* cp = Cq + (size_t)row * HID_ + n0 + wn * 64 + li;
                cp[0]  = __float2bfloat16(y0);
                cp[16] = __float2bfloat16(y1);
                cp[32] = __float2bfloat16(y2);
                cp[48] = __float2bfloat16(y3);
            } else {
                bf16* cp = Ck + (size_t)row * 512 + cb + wn * 64 + li;
                cp[0]  = __float2bfloat16(y0);
                cp[16] = __float2bfloat16(y1);
                cp[32] = __float2bfloat16(y2);
                cp[48] = __float2bfloat16(y3);
            }
        }
    }
}

// ---------------------------------------------------------------------------
// MFMA flash attention (compute path identical to the verified ~115us kernel).
// blockIdx.y >= 64 -> absorbed wtrans of wo -> woT (runs in attn's shadow;
// woT overlays wqkvT, dead after gemm<0>). LDS merged into one block so the
// wtrans branch aliases it (32 KB total unchanged).
// ---------------------------------------------------------------------------
__global__ __launch_bounds__(256, 4) void attn_k(
    const bf16* __restrict__ qws, const bf16* __restrict__ kws,
    const bf16* __restrict__ vtw, bf16* __restrict__ ows,
    const float* __restrict__ wo, bf16* __restrict__ woT)
{
    __shared__ unsigned short sMem[16384];   // 32 KB: sK|sVt|sP

    if (blockIdx.y >= 64) {
        const int t = (blockIdx.y - 64) * 16 + blockIdx.x;  // 0..1023 (32 x 32)
        wtrans_body(wo, 2048, wo, 0, wo, 0, woT, HID_, t & 31, t >> 5, sMem);
        return;
    }

    unsigned short* sK  = sMem;             // [key][dim], swizzled (4096)
    unsigned short* sVt = sMem + 4096;      // [dim][key], swizzled (4096)
    unsigned short* sP  = sMem + 8192;      // per-wave [2*16 q][key] (8192)

    const int tid  = threadIdx.x;
    const int wave = tid >> 6, lane = tid & 63;
    const int li   = lane & 15, lj = lane >> 4;
    const int bh   = blockIdx.y;
    const int q0   = blockIdx.x * 128;
    const int b    = bh / NH_, h = bh % NH_;
    const int hk   = h / G_;

    bf16x8 qf[2][2];
    #pragma unroll
    for (int g = 0; g < 2; g++) {
        const bf16* qp = qws + (size_t)(b * S_ + q0 + wave * 32 + g * 16 + li) * HID_
                         + h * D_ + lj * 8;
        qf[g][0] = *(const bf16x8*)(qp);
        qf[g][1] = *(const bf16x8*)(qp + 32);
    }

    f32x4 o[2][4];
    #pragma unroll
    for (int g = 0; g < 2; g++)
        #pragma unroll
        for (int mt = 0; mt < 4; mt++) o[g][mt] = (f32x4){0.f, 0.f, 0.f, 0.f};
    float mr[2] = {-1e30f, -1e30f};
    float ll[2] = {0.f, 0.f};

    const int srow = tid >> 2, scol = (tid & 3) * 16;
    const bf16* kb = kws + (size_t)b * S_ * 512 + hk * 64;
    const bf16* vb = vtw + (size_t)((b * NKV_ + hk) * 64) * S_;
    unsigned short* sp = sP + wave * (32 * 64);

    uint4 pk0, pk1, pv0, pv1;
    {
        const uint4* kp = (const uint4*)(kb + (size_t)srow * 512 + scol);
        const uint4* vp = (const uint4*)(vb + (size_t)srow * S_ + scol);
        pk0 = kp[0]; pk1 = kp[1]; pv0 = vp[0]; pv1 = vp[1];
    }

    for (int kt = 0; kt < S_; kt += 64) {
        __syncthreads();
        *(uint4*)&sK [srow * 64 + SWZ(srow, scol)]     = pk0;
        *(uint4*)&sK [srow * 64 + SWZ(srow, scol + 8)] = pk1;
        *(uint4*)&sVt[srow * 64 + SWZ(srow, scol)]     = pv0;
        *(uint4*)&sVt[srow * 64 + SWZ(srow, scol + 8)] = pv1;
        __syncthreads();

        if (kt + 64 < S_) {
            const uint4* kp = (const uint4*)(kb + (size_t)(kt + 64 + srow) * 512 + scol);
            const uint4* vp = (const uint4*)(vb + (size_t)srow * S_ + kt + 64 + scol);
            pk0 = kp[0]; pk1 = kp[1]; pv0 = vp[0]; pv1 = vp[1];
        }

        float sc[2][4][4];
        __builtin_amdgcn_s_setprio(1);
        #pragma unroll
        for (int nt = 0; nt < 4; nt++) {
            f32x4 c0 = (f32x4){0.f, 0.f, 0.f, 0.f};
            f32x4 c1 = (f32x4){0.f, 0.f, 0.f, 0.f};
            #pragma unroll
            for (int ks = 0; ks < 2; ks++) {
                const bf16x8 kf =
                    *(const bf16x8*)&sK[(nt * 16 + li) * 64 + SWZ(li, ks * 32 + lj * 8)];
                c0 = __builtin_amdgcn_mfma_f32_16x16x32_bf16(kf, qf[0][ks], c0, 0, 0, 0);
                c1 = __builtin_amdgcn_mfma_f32_16x16x32_bf16(kf, qf[1][ks], c1, 0, 0, 0);
            }
            #pragma unroll
            for (int r = 0; r < 4; r++) { sc[0][nt][r] = c0[r]; sc[1][nt][r] = c1[r]; }
        }
        __builtin_amdgcn_s_setprio(0);

        #pragma unroll
        for (int g = 0; g < 2; g++) {
            float cm = sc[g][0][0];
            #pragma unroll
            for (int nt = 0; nt < 4; nt++)
                #pragma unroll
                for (int r = 0; r < 4; r++) cm = fmaxf(cm, sc[g][nt][r]);
            cm = fmaxf(cm, __shfl_xor(cm, 16));
            cm = fmaxf(cm, __shfl_xor(cm, 32));
            if (!__all(cm - mr[g] <= 8.0f)) {
                const float mnew = fmaxf(mr[g], cm);
                const float al   = fexp2(mr[g] - mnew);
                mr[g] = mnew;
                ll[g] *= al;
                #pragma unroll
                for (int mt = 0; mt < 4; mt++) o[g][mt] *= al;
            }
            float rs = 0.f;
            #pragma unroll
            for (int nt = 0; nt < 4; nt++) {
                const float e0 = fexp2(sc[g][nt][0] - mr[g]);
                const float e1 = fexp2(sc[g][nt][1] - mr[g]);
                const float e2 = fexp2(sc[g][nt][2] - mr[g]);
                const float e3 = fexp2(sc[g][nt][3] - mr[g]);
                rs += (e0 + e1) + (e2 + e3);
                u16x4 u = { f2bfu(e0), f2bfu(e1), f2bfu(e2), f2bfu(e3) };
                *(u16x4*)&sp[(g * 16 + li) * 64 + SWZ(li, nt * 16 + lj * 4)] = u;
            }
            ll[g] += rs;
        }

        __builtin_amdgcn_s_setprio(1);
        #pragma unroll
        for (int ks = 0; ks < 2; ks++) {
            const bf16x8 pf0 = *(const bf16x8*)&sp[(li)      * 64 + SWZ(li, ks * 32 + lj * 8)];
            const bf16x8 pf1 = *(const bf16x8*)&sp[(16 + li) * 64 + SWZ(li, ks * 32 + lj * 8)];
            #pragma unroll
            for (int mt = 0; mt < 4; mt++) {
                const bf16x8 vf =
                    *(const bf16x8*)&sVt[(mt * 16 + li) * 64 + SWZ(li, ks * 32 + lj * 8)];
                o[0][mt] = __builtin_amdgcn_mfma_f32_16x16x32_bf16(vf, pf0, o[0][mt], 0, 0, 0);
                o[1][mt] = __builtin_amdgcn_mfma_f32_16x16x32_bf16(vf, pf1, o[1][mt], 0, 0, 0);
            }
        }
        __builtin_amdgcn_s_setprio(0);
    }

    #pragma unroll
    for (int g = 0; g < 2; g++) {
        float l = ll[g];
        l += __shfl_xor(l, 16);
        l += __shfl_xor(l, 32);
        const float inv = 1.0f / l;
        bf16* op = ows + (size_t)(b * S_ + q0 + wave * 32 + g * 16 + li) * HID_ + h * D_;
        #pragma unroll
        for (int mt = 0; mt < 4; mt++) {
            u16x4 u = { f2bfu(o[g][mt][0] * inv), f2bfu(o[g][mt][1] * inv),
                        f2bfu(o[g][mt][2] * inv), f2bfu(o[g][mt][3] * inv) };
            *(u16x4*)((unsigned short*)op + mt * 16 + lj * 4) = u;
        }
    }
}

// ---------------------------------------------------------------------------
extern "C" void kernel_launch(void* const* d_in, const int* in_sizes, int n_in,
                              void* d_out, int out_size, void* d_ws, size_t ws_size,
                              hipStream_t stream)
{
    const float* hs  = (const float*)d_in[0];
    const int*   pos = (const int*)d_in[1];
    const float* wq = (const float*)d_in[2];
    const float* bq = (const float*)d_in[3];
    const float* wk = (const float*)d_in[4];
    const float* bk = (const float*)d_in[5];
    const float* wv = (const float*)d_in[6];
    const float* bv = (const float*)d_in[7];
    const float* wo = (const float*)d_in[8];
    const float* bo = (const float*)d_in[9];

    // workspace (52.5 MB peak)
    char* ws = (char*)d_ws;
    float* ctab  = (float*)(ws);
    float* stab  = (float*)(ws + (256u << 10));
    bf16*  k_ws  = (bf16*)(ws + (512u << 10));
    bf16*  v_t   = (bf16*)(ws + (512u << 10) + (4u  << 20));
    bf16*  q_ws  = (bf16*)(ws + (512u << 10) + (8u  << 20));
    bf16*  hs_b  = (bf16*)(ws + (512u << 10) + (24u << 20));
    bf16*  o_ws  = hs_b;                                   // overlay
    bf16*  wqkvT = (bf16*)(ws + (512u << 10) + (40u << 20));
    bf16*  woT   = wqkvT;                                  // overlay (dead after gemm<0>)

    // prep: cvt (4096) + wtrans qkv (1536) + rope (256)
    prep_k<<<dim3(5888), dim3(256), 0, stream>>>(
        hs, hs_b, wq, wk, wv, wqkvT, pos, ctab, stab);

    // QKV: BM=256, BN=256 -> grid 12 x 16 = 192 blocks
    gemm8p_k<0, 256><<<dim3(12, 16), dim3(512), 0, stream>>>(
        hs_b, wqkvT, bq, bk, bv, q_ws, k_ws, v_t, nullptr, ctab, stab);

    // attn (y<64) + absorbed wtrans wo -> woT (y>=64)
    attn_k<<<dim3(16, 128), dim3(256), 0, stream>>>(
        q_ws, k_ws, v_t, o_ws, wo, woT);

    // OUT: BM=128, BN=256 -> grid 8 x 32 = 256 blocks (exactly 1/CU)
    gemm8p_k<1, 128><<<dim3(8, 32), dim3(512), 0, stream>>>(
        o_ws, woT, bo, nullptr, nullptr, nullptr, nullptr, nullptr,
        (float*)d_out, nullptr, nullptr);
}

// Round 5
// 320.973 us; speedup vs baseline: 1.2448x; 1.0126x over previous
//
#include <hip/hip_runtime.h>
#include <hip/hip_bf16.h>
#include <math.h>

#define B_   2
#define S_   2048
#define HID_ 2048
#define NH_  32
#define NKV_ 8
#define D_   64
#define G_   (NH_/NKV_)
#define M_   (B_*S_)      // 4096

typedef __hip_bfloat16 bf16;
typedef short bf16x8 __attribute__((ext_vector_type(8)));
typedef float f32x4  __attribute__((ext_vector_type(4)));
typedef unsigned short u16x4 __attribute__((ext_vector_type(4)));

__device__ inline unsigned short f2bfu(float f){
    __hip_bfloat16 h = __float2bfloat16(f);
    return __builtin_bit_cast(unsigned short, h);
}

__device__ __forceinline__ float fexp2(float x){
#if __has_builtin(__builtin_amdgcn_exp2f)
    return __builtin_amdgcn_exp2f(x);
#else
    return exp2f(x);
#endif
}

// async global->LDS, 16B per lane. LDS dest = wave-uniform base + lane*16.
__device__ __forceinline__ void async16(const void* g, void* l) {
    __builtin_amdgcn_global_load_lds(
        (const __attribute__((address_space(1))) unsigned int*)g,
        (__attribute__((address_space(3))) unsigned int*)l, 16, 0, 0);
}

// XOR swizzle for 128B (64 ushort) rows (attn): spreads 16B slots across banks.
#define SWZ(r, c) ((c) ^ (((r) & 7) << 3))

// raw barrier + counted waitcnt
#define S_BARRIER() asm volatile("s_barrier" ::: "memory")
__device__ __forceinline__ void vmwait4(){ asm volatile("s_waitcnt vmcnt(4)" ::: "memory"); }
__device__ __forceinline__ void vmwait0(){ asm volatile("s_waitcnt vmcnt(0)" ::: "memory"); }

// ---------------------------------------------------------------------------
// Transpose + convert body: dst[n][k] (bf16) = src_seg[k][n] (fp32).
// tbuf must hold >= 64*65 ushorts of LDS.
// ---------------------------------------------------------------------------
__device__ __forceinline__ void wtrans_body(
    const float* __restrict__ s0, int N0,
    const float* __restrict__ s1, int N1,
    const float* __restrict__ s2, int N2,
    bf16* __restrict__ dst, int K, int bx, int by,
    unsigned short* __restrict__ tbuf)
{
    unsigned short (*t)[65] = (unsigned short (*)[65])tbuf;
    const int ntile = bx * 64, ktile = by * 64;
    const float* src; int nloc, Nseg;
    if (ntile < N0)           { src = s0; nloc = ntile;           Nseg = N0; }
    else if (ntile < N0 + N1) { src = s1; nloc = ntile - N0;      Nseg = N1; }
    else                      { src = s2; nloc = ntile - N0 - N1; Nseg = N2; }
    const int r  = threadIdx.x >> 4;
    const int c4 = (threadIdx.x & 15) * 4;
    #pragma unroll
    for (int p = 0; p < 4; p++) {
        const int k = p * 16 + r;
        const float4 f = *(const float4*)(src + (size_t)(ktile + k) * Nseg + nloc + c4);
        t[k][c4+0] = f2bfu(f.x); t[k][c4+1] = f2bfu(f.y);
        t[k][c4+2] = f2bfu(f.z); t[k][c4+3] = f2bfu(f.w);
    }
    __syncthreads();
    #pragma unroll
    for (int p = 0; p < 4; p++) {
        const int n = p * 16 + r;
        u16x4 u = { t[c4+0][n], t[c4+1][n], t[c4+2][n], t[c4+3][n] };
        *(u16x4*)((unsigned short*)dst + (size_t)(ntile + n) * K + ktile + c4) = u;
    }
}

// ---------------------------------------------------------------------------
// Fused prep: blocks [0,4096) fp32->bf16 convert of hidden_states;
//             [4096,5632) wtrans of wq|wk|wv -> wqkvT;
//             [5632,5888) RoPE cos/sin tables.
// ---------------------------------------------------------------------------
__global__ __launch_bounds__(256) void prep_k(
    const float* __restrict__ hs, bf16* __restrict__ hs_b,
    const float* __restrict__ wq, const float* __restrict__ wk,
    const float* __restrict__ wv, bf16* __restrict__ wqkvT,
    const int* __restrict__ pos, float* __restrict__ ctab,
    float* __restrict__ stab)
{
    __shared__ unsigned short tbuf[64 * 65];
    const int bid = blockIdx.x;
    if (bid < 4096) {
        const int i = (bid * 256 + threadIdx.x) * 8;
        const float4 a = *(const float4*)(hs + i);
        const float4 b = *(const float4*)(hs + i + 4);
        uint4 u;
        u.x = (unsigned)f2bfu(a.x) | ((unsigned)f2bfu(a.y) << 16);
        u.y = (unsigned)f2bfu(a.z) | ((unsigned)f2bfu(a.w) << 16);
        u.z = (unsigned)f2bfu(b.x) | ((unsigned)f2bfu(b.y) << 16);
        u.w = (unsigned)f2bfu(b.z) | ((unsigned)f2bfu(b.w) << 16);
        *(uint4*)((unsigned short*)hs_b + i) = u;
    } else if (bid < 5632) {
        const int t = bid - 4096;                       // 0..1535 (48 x 32)
        wtrans_body(wq, 2048, wk, 512, wv, 512, wqkvT, HID_,
                    t % 48, t / 48, tbuf);
    } else {
        const int idx = (bid - 5632) * 256 + threadIdx.x;
        const int s = idx >> 5, i = idx & 31;
        const int is64 = (pos[1] == 0);
        const int p = is64 ? pos[2 * s] : pos[s];
        const double inv = exp(-(double)i * (log(150000.0) / 32.0));
        const double f = (double)p * inv;
        ctab[idx] = (float)cos(f);
        stab[idx] = (float)sin(f);
    }
}

// ---------------------------------------------------------------------------
// 8-phase pipelined MFMA GEMM (m201-style): C = A[M,2048] @ WT[N,2048]^T.
// BM x 256 tile, BK=64, 8 waves (2M x 4N), double-buffered LDS.
// Counted vmcnt(4) only twice per 2-tile iteration; XOR chunk swizzle
// both-sides. T1: XCD-chunked block remap.
// MODE 0: QKV epilogue (Q: RoPE + 0.125*log2e; K: RoPE; V: transposed store).
// MODE 1: OUT epilogue (fp32 + bias b0), BM=128.
// ---------------------------------------------------------------------------
__device__ __forceinline__ void slab64(
    const bf16* __restrict__ g, int grow0, int k0,
    unsigned short* lds, int wave, int lane)
{
    const int rr = wave * 8 + (lane >> 3);
    const int cc = ((lane & 7) ^ (lane >> 3)) * 8;
    async16(g + (size_t)(grow0 + rr) * 2048 + k0 + cc, lds + wave * 512);
}

template<int MODE, int BM>
__global__ __launch_bounds__(512, 2) void gemm8p_k(
    const bf16* __restrict__ A, const bf16* __restrict__ WT,
    const float* __restrict__ b0, const float* __restrict__ b1,
    const float* __restrict__ b2,
    bf16* __restrict__ Cq, bf16* __restrict__ Ck, bf16* __restrict__ Cv,
    float* __restrict__ Cout,
    const float* __restrict__ ctab, const float* __restrict__ stab)
{
    constexpr int MT = BM / 32;    // m-frags per wave
    constexpr int PM = MT / 4;     // m-frags per phase (quadrant)
    constexpr int LA = BM * 64;    // ushorts per A buffer
    constexpr int LB = 256 * 64;   // ushorts per B buffer
    constexpr int NT = 32;         // K-tiles (2048/64)
    __shared__ unsigned short sA[2 * LA];
    __shared__ unsigned short sB[2 * LB];

    const int tid  = threadIdx.x;
    const int wave = tid >> 6, lane = tid & 63;
    const int li   = lane & 15, lj = lane >> 4;
    const int wm   = wave >> 2, wn = wave & 3;

    // T1: XCD-chunked bijective remap (nwg % 8 == 0 for both instantiations).
    const int nbx = gridDim.x, nby = gridDim.y;
    const int lin = blockIdx.y * nbx + blockIdx.x;
    const int qq  = (nbx * nby) >> 3;
    const int logical = (lin & 7) * qq + (lin >> 3);
    const int m0 = (logical % nby) * BM;
    const int n0 = (logical / nby) * 256;
    const int swz = li & 7;

    f32x4 acc[MT][4];
    #pragma unroll
    for (int i = 0; i < MT; ++i)
        #pragma unroll
        for (int j = 0; j < 4; ++j)
            acc[i][j] = (f32x4){0.f, 0.f, 0.f, 0.f};

    bf16x8 bfr[4][2];

    auto stageA = [&](int t, int r0) {
        unsigned short* l = sA + (t & 1) * LA + r0 * 64;
        const int k0 = (t & (NT - 1)) * 64;
        slab64(A, m0 + r0,      k0, l,           wave, lane);
        slab64(A, m0 + r0 + 64, k0, l + 64 * 64, wave, lane);
    };
    auto stageB = [&](int t, int r0) {
        unsigned short* l = sB + (t & 1) * LB + r0 * 64;
        const int k0 = (t & (NT - 1)) * 64;
        slab64(WT, n0 + r0,      k0, l,           wave, lane);
        slab64(WT, n0 + r0 + 64, k0, l + 64 * 64, wave, lane);
    };
    auto ldB = [&](int tb) {
        const unsigned short* base = sB + tb * LB;
        #pragma unroll
        for (int nt = 0; nt < 4; ++nt)
            #pragma unroll
            for (int ks = 0; ks < 2; ++ks)
                bfr[nt][ks] = *(const bf16x8*)
                    &base[(wn * 64 + nt * 16 + li) * 64 + ((ks * 4 + lj) ^ swz) * 8];
    };
    auto ldA = [&](int tb, int q, bf16x8 (*af)[2]) {
        const unsigned short* base = sA + tb * LA;
        #pragma unroll
        for (int m = 0; m < PM; ++m)
            #pragma unroll
            for (int ks = 0; ks < 2; ++ks)
                af[m][ks] = *(const bf16x8*)
                    &base[(wm * (BM / 2) + (q * PM + m) * 16 + li) * 64
                          + ((ks * 4 + lj) ^ swz) * 8];
    };
    auto mfma_q = [&](int q, bf16x8 (*af)[2]) {
        __builtin_amdgcn_s_setprio(1);
        #pragma unroll
        for (int ks = 0; ks < 2; ++ks)
            #pragma unroll
            for (int m = 0; m < PM; ++m)
                #pragma unroll
                for (int nt = 0; nt < 4; ++nt)
                    acc[q * PM + m][nt] = __builtin_amdgcn_mfma_f32_16x16x32_bf16(
                        af[m][ks], bfr[nt][ks], acc[q * PM + m][nt], 0, 0, 0);
        __builtin_amdgcn_s_setprio(0);
    };

    // prologue: tile 0 (A+B) + B(1); vmcnt(4) leaves B(1) in flight.
    stageA(0, 0);
    if constexpr (BM == 256) stageA(0, 128);
    stageB(0, 0); stageB(0, 128);
    stageB(1, 0); stageB(1, 128);
    vmwait4();
    S_BARRIER();

    for (int i = 0; i < NT / 2; ++i) {
        const int ta = 2 * i, tb = 2 * i + 1;
        bf16x8 af0[PM][2], af1[PM][2], af2[PM][2], af3[PM][2];
        // ---- tile ta (buf0) ----
        ldB(0); ldA(0, 0, af0);
        stageA(tb, 0);
        S_BARRIER(); mfma_q(0, af0); S_BARRIER();
        ldA(0, 1, af1);
        if constexpr (BM == 256) stageA(tb, 128);
        S_BARRIER(); mfma_q(1, af1); S_BARRIER();
        ldA(0, 2, af2);
        stageB(ta + 2, 0);
        S_BARRIER(); mfma_q(2, af2); S_BARRIER();
        ldA(0, 3, af3);
        stageB(ta + 2, 128);
        S_BARRIER(); mfma_q(3, af3);
        vmwait4();
        S_BARRIER();
        // ---- tile tb (buf1) ----
        ldB(1); ldA(1, 0, af0);
        stageA(ta + 2, 0);
        S_BARRIER(); mfma_q(0, af0); S_BARRIER();
        ldA(1, 1, af1);
        if constexpr (BM == 256) stageA(ta + 2, 128);
        S_BARRIER(); mfma_q(1, af1); S_BARRIER();
        ldA(1, 2, af2);
        stageB(tb + 2, 0);
        S_BARRIER(); mfma_q(2, af2); S_BARRIER();
        ldA(1, 3, af3);
        stageB(tb + 2, 128);
        S_BARRIER(); mfma_q(3, af3);
        vmwait4();
        S_BARRIER();
    }
    vmwait0();
    S_BARRIER();

    // ------------------------------ epilogue ------------------------------
    if (MODE == 1) {
        #pragma unroll
        for (int mt = 0; mt < MT; ++mt)
            #pragma unroll
            for (int nt = 0; nt < 4; ++nt) {
                const int col = n0 + wn * 64 + nt * 16 + li;
                const float bb = b0[col];
                #pragma unroll
                for (int r = 0; r < 4; ++r) {
                    const int row = m0 + wm * (BM / 2) + mt * 16 + lj * 4 + r;
                    Cout[(size_t)row * HID_ + col] = acc[mt][nt][r] + bb;
                }
            }
        return;
    }

    int seg, cb; const float* bias;
    if (n0 < 2048)      { seg = 0; cb = n0;        bias = b0; }
    else if (n0 < 2560) { seg = 1; cb = n0 - 2048; bias = b1; }
    else                { seg = 2; cb = n0 - 2560; bias = b2; }

    float bl[4];
    #pragma unroll
    for (int nt = 0; nt < 4; ++nt) bl[nt] = bias[cb + wn * 64 + nt * 16 + li];

    if (seg == 2) {
        const int b = m0 >> 11;
        #pragma unroll
        for (int nt = 0; nt < 4; ++nt) {
            const int cseg = cb + wn * 64 + nt * 16 + li;
            const int hv = cseg >> 6, d = cseg & 63;
            #pragma unroll
            for (int mt = 0; mt < MT; ++mt) {
                const int sb = (m0 & (S_ - 1)) + wm * (BM / 2) + mt * 16 + lj * 4;
                u16x4 u = { f2bfu(acc[mt][nt][0] + bl[nt]),
                            f2bfu(acc[mt][nt][1] + bl[nt]),
                            f2bfu(acc[mt][nt][2] + bl[nt]),
                            f2bfu(acc[mt][nt][3] + bl[nt]) };
                *(u16x4*)((unsigned short*)Cv +
                    ((size_t)((b * NKV_ + hv) * 64 + d)) * S_ + sb) = u;
            }
        }
        return;
    }

    const float qs = (seg == 0) ? 0.18033688011112042f : 1.0f;
    #pragma unroll
    for (int mt = 0; mt < MT; ++mt) {
        #pragma unroll
        for (int r = 0; r < 4; ++r) {
            const int row = m0 + wm * (BM / 2) + mt * 16 + lj * 4 + r;
            const int s = row & (S_ - 1);
            const float c0  = ctab[s * 32 + li],      sn0 = stab[s * 32 + li];
            const float c1  = ctab[s * 32 + 16 + li], sn1 = stab[s * 32 + 16 + li];
            const float x0 = acc[mt][0][r] + bl[0];
            const float x1 = acc[mt][1][r] + bl[1];
            const float x2 = acc[mt][2][r] + bl[2];
            const float x3 = acc[mt][3][r] + bl[3];
            const float y0 = (x0 * c0 - x2 * sn0) * qs;
            const float y2 = (x2 * c0 + x0 * sn0) * qs;
            const float y1 = (x1 * c1 - x3 * sn1) * qs;
            const float y3 = (x3 * c1 + x1 * sn1) * qs;
            if (seg == 0) {
                bf16* cp = Cq + (size_t)row * HID_ + n0 + wn * 64 + li;
                cp[0]  = __float2bfloat16(y0);
                cp[16] = __float2bfloat16(y1);
                cp[32] = __float2bfloat16(y2);
                cp[48] = __float2bfloat16(y3);
            } else {
                bf16* cp = Ck + (size_t)row * 512 + cb + wn * 64 + li;
                cp[0]  = __float2bfloat16(y0);
                cp[16] = __float2bfloat16(y1);
                cp[32] = __float2bfloat16(y2);
                cp[48] = __float2bfloat16(y3);
            }
        }
    }
}

// ---------------------------------------------------------------------------
// MFMA flash attention v3: QBLK=256, 64 q-rows per wave (4 q-groups of 16).
// The kernel is LDS-throughput-bound (validated cycle model == measured dur):
// kf/vf frags and K/V staging are q-independent, so caching kf/vf in
// REGISTERS once per tile and reusing across 4 q-groups cuts LDS cycles
// per q-row from ~8.4 to ~6.0 and blocks/CU batches from 8 to 2.
// blockIdx.y >= 64 -> absorbed wtrans of wo -> woT.
// ---------------------------------------------------------------------------
__global__ __launch_bounds__(256, 2) void attn_k(
    const bf16* __restrict__ qws, const bf16* __restrict__ kws,
    const bf16* __restrict__ vtw, bf16* __restrict__ ows,
    const float* __restrict__ wo, bf16* __restrict__ woT)
{
    __shared__ unsigned short sMem[24576];   // 48 KB: sK(8K) | sVt(8K) | sP(32K)

    if (blockIdx.y >= 64) {
        const int t = (blockIdx.y - 64) * 8 + blockIdx.x;   // 0..1023 (32 x 32)
        wtrans_body(wo, 2048, wo, 0, wo, 0, woT, HID_, t & 31, t >> 5, sMem);
        return;
    }

    unsigned short* sK  = sMem;             // [key][dim], swizzled (4096)
    unsigned short* sVt = sMem + 4096;      // [dim][key], swizzled (4096)
    unsigned short* sP  = sMem + 8192;      // per-wave [4*16 q][key] (16384)

    const int tid  = threadIdx.x;
    const int wave = tid >> 6, lane = tid & 63;
    const int li   = lane & 15, lj = lane >> 4;
    const int bh   = blockIdx.y;
    const int q0   = blockIdx.x * 256;
    const int b    = bh / NH_, h = bh % NH_;
    const int hk   = h / G_;

    bf16x8 qf[4][2];
    #pragma unroll
    for (int g = 0; g < 4; g++) {
        const bf16* qp = qws + (size_t)(b * S_ + q0 + wave * 64 + g * 16 + li) * HID_
                         + h * D_ + lj * 8;
        qf[g][0] = *(const bf16x8*)(qp);
        qf[g][1] = *(const bf16x8*)(qp + 32);
    }

    f32x4 o[4][4];
    #pragma unroll
    for (int g = 0; g < 4; g++)
        #pragma unroll
        for (int mt = 0; mt < 4; mt++) o[g][mt] = (f32x4){0.f, 0.f, 0.f, 0.f};
    float mr[4] = {-1e30f, -1e30f, -1e30f, -1e30f};
    float ll[4] = {0.f, 0.f, 0.f, 0.f};

    const int srow = tid >> 2, scol = (tid & 3) * 16;
    const bf16* kb = kws + (size_t)b * S_ * 512 + hk * 64;
    const bf16* vb = vtw + (size_t)((b * NKV_ + hk) * 64) * S_;
    unsigned short* sp = sP + wave * (64 * 64);

    uint4 pk0, pk1, pv0, pv1;
    {
        const uint4* kp = (const uint4*)(kb + (size_t)srow * 512 + scol);
        const uint4* vp = (const uint4*)(vb + (size_t)srow * S_ + scol);
        pk0 = kp[0]; pk1 = kp[1]; pv0 = vp[0]; pv1 = vp[1];
    }

    for (int kt = 0; kt < S_; kt += 64) {
        __syncthreads();
        *(uint4*)&sK [srow * 64 + SWZ(srow, scol)]     = pk0;
        *(uint4*)&sK [srow * 64 + SWZ(srow, scol + 8)] = pk1;
        *(uint4*)&sVt[srow * 64 + SWZ(srow, scol)]     = pv0;
        *(uint4*)&sVt[srow * 64 + SWZ(srow, scol + 8)] = pv1;
        __syncthreads();

        if (kt + 64 < S_) {
            const uint4* kp = (const uint4*)(kb + (size_t)(kt + 64 + srow) * 512 + scol);
            const uint4* vp = (const uint4*)(vb + (size_t)srow * S_ + kt + 64 + scol);
            pk0 = kp[0]; pk1 = kp[1]; pv0 = vp[0]; pv1 = vp[1];
        }

        // K frags once into registers; reused by all 4 q-groups.
        bf16x8 kf[4][2];
        #pragma unroll
        for (int nt = 0; nt < 4; nt++)
            #pragma unroll
            for (int ks = 0; ks < 2; ks++)
                kf[nt][ks] = *(const bf16x8*)&sK[(nt * 16 + li) * 64
                                                 + SWZ(li, ks * 32 + lj * 8)];

        // per q-group: QK^T -> online softmax -> P store
        #pragma unroll
        for (int g = 0; g < 4; g++) {
            f32x4 c[4];
            __builtin_amdgcn_s_setprio(1);
            #pragma unroll
            for (int nt = 0; nt < 4; nt++) {
                c[nt] = (f32x4){0.f, 0.f, 0.f, 0.f};
                #pragma unroll
                for (int ks = 0; ks < 2; ks++)
                    c[nt] = __builtin_amdgcn_mfma_f32_16x16x32_bf16(
                        kf[nt][ks], qf[g][ks], c[nt], 0, 0, 0);
            }
            __builtin_amdgcn_s_setprio(0);

            float cm = c[0][0];
            #pragma unroll
            for (int nt = 0; nt < 4; nt++)
                #pragma unroll
                for (int r = 0; r < 4; r++) cm = fmaxf(cm, c[nt][r]);
            cm = fmaxf(cm, __shfl_xor(cm, 16));
            cm = fmaxf(cm, __shfl_xor(cm, 32));
            if (!__all(cm - mr[g] <= 8.0f)) {
                const float mnew = fmaxf(mr[g], cm);
                const float al   = fexp2(mr[g] - mnew);
                mr[g] = mnew;
                ll[g] *= al;
                #pragma unroll
                for (int mt = 0; mt < 4; mt++) o[g][mt] *= al;
            }
            float rs = 0.f;
            #pragma unroll
            for (int nt = 0; nt < 4; nt++) {
                const float e0 = fexp2(c[nt][0] - mr[g]);
                const float e1 = fexp2(c[nt][1] - mr[g]);
                const float e2 = fexp2(c[nt][2] - mr[g]);
                const float e3 = fexp2(c[nt][3] - mr[g]);
                rs += (e0 + e1) + (e2 + e3);
                u16x4 u = { f2bfu(e0), f2bfu(e1), f2bfu(e2), f2bfu(e3) };
                *(u16x4*)&sp[(g * 16 + li) * 64 + SWZ(li, nt * 16 + lj * 4)] = u;
            }
            ll[g] += rs;   // lane-local partial; reduced once in epilogue
        }

        // V frags once into registers; reused by all 4 q-groups.
        bf16x8 vf[4][2];
        #pragma unroll
        for (int mt = 0; mt < 4; mt++)
            #pragma unroll
            for (int ks = 0; ks < 2; ks++)
                vf[mt][ks] = *(const bf16x8*)&sVt[(mt * 16 + li) * 64
                                                  + SWZ(li, ks * 32 + lj * 8)];

        __builtin_amdgcn_s_setprio(1);
        #pragma unroll
        for (int g = 0; g < 4; g++) {
            #pragma unroll
            for (int ks = 0; ks < 2; ks++) {
                const bf16x8 pf = *(const bf16x8*)&sp[(g * 16 + li) * 64
                                                      + SWZ(li, ks * 32 + lj * 8)];
                #pragma unroll
                for (int mt = 0; mt < 4; mt++)
                    o[g][mt] = __builtin_amdgcn_mfma_f32_16x16x32_bf16(
                        vf[mt][ks], pf, o[g][mt], 0, 0, 0);
            }
        }
        __builtin_amdgcn_s_setprio(0);
    }

    #pragma unroll
    for (int g = 0; g < 4; g++) {
        float l = ll[g];
        l += __shfl_xor(l, 16);
        l += __shfl_xor(l, 32);
        const float inv = 1.0f / l;
        bf16* op = ows + (size_t)(b * S_ + q0 + wave * 64 + g * 16 + li) * HID_ + h * D_;
        #pragma unroll
        for (int mt = 0; mt < 4; mt++) {
            u16x4 u = { f2bfu(o[g][mt][0] * inv), f2bfu(o[g][mt][1] * inv),
                        f2bfu(o[g][mt][2] * inv), f2bfu(o[g][mt][3] * inv) };
            *(u16x4*)((unsigned short*)op + mt * 16 + lj * 4) = u;
        }
    }
}

// ---------------------------------------------------------------------------
extern "C" void kernel_launch(void* const* d_in, const int* in_sizes, int n_in,
                              void* d_out, int out_size, void* d_ws, size_t ws_size,
                              hipStream_t stream)
{
    const float* hs  = (const float*)d_in[0];
    const int*   pos = (const int*)d_in[1];
    const float* wq = (const float*)d_in[2];
    const float* bq = (const float*)d_in[3];
    const float* wk = (const float*)d_in[4];
    const float* bk = (const float*)d_in[5];
    const float* wv = (const float*)d_in[6];
    const float* bv = (const float*)d_in[7];
    const float* wo = (const float*)d_in[8];
    const float* bo = (const float*)d_in[9];

    // workspace (52.5 MB peak)
    char* ws = (char*)d_ws;
    float* ctab  = (float*)(ws);
    float* stab  = (float*)(ws + (256u << 10));
    bf16*  k_ws  = (bf16*)(ws + (512u << 10));
    bf16*  v_t   = (bf16*)(ws + (512u << 10) + (4u  << 20));
    bf16*  q_ws  = (bf16*)(ws + (512u << 10) + (8u  << 20));
    bf16*  hs_b  = (bf16*)(ws + (512u << 10) + (24u << 20));
    bf16*  o_ws  = hs_b;                                   // overlay
    bf16*  wqkvT = (bf16*)(ws + (512u << 10) + (40u << 20));
    bf16*  woT   = wqkvT;                                  // overlay (dead after gemm<0>)

    // prep: cvt (4096) + wtrans qkv (1536) + rope (256)
    prep_k<<<dim3(5888), dim3(256), 0, stream>>>(
        hs, hs_b, wq, wk, wv, wqkvT, pos, ctab, stab);

    // QKV: BM=256, BN=256 -> grid 12 x 16 = 192 blocks
    gemm8p_k<0, 256><<<dim3(12, 16), dim3(512), 0, stream>>>(
        hs_b, wqkvT, bq, bk, bv, q_ws, k_ws, v_t, nullptr, ctab, stab);

    // attn (y<64, QBLK=256) + absorbed wtrans wo -> woT (y in [64,192))
    attn_k<<<dim3(8, 192), dim3(256), 0, stream>>>(
        q_ws, k_ws, v_t, o_ws, wo, woT);

    // OUT: BM=128, BN=256 -> grid 8 x 32 = 256 blocks (exactly 1/CU)
    gemm8p_k<1, 128><<<dim3(8, 32), dim3(512), 0, stream>>>(
        o_ws, woT, bo, nullptr, nullptr, nullptr, nullptr, nullptr,
        (float*)d_out, nullptr, nullptr);
}